// Round 5
// baseline (410.873 us; speedup 1.0000x reference)
//
#include <hip/hip_runtime.h>

#define BATCH 256
#define NP 64
#define DIM 512
#define NH 8
#define SCALE 0.125f

typedef __attribute__((ext_vector_type(4))) float f32x4;
typedef __attribute__((ext_vector_type(8))) short bf16x8;

// ---------------- workspace layout (bytes) ----------------
// C   [0, 8192)            bf16 C[64][64], swizzled (W2-MFMA A-operand layout)
// U   [8192, 4202496)      f32 [256][8][512]
// Y   [4202496, 8396800)   f32 [256][8][512]
// O   [8396800, 8921088)   f32 [256][512]
// S   [8921088, 9445376)   f32 [256][512]
#define WS_C 0
#define WS_U 8192
#define WS_Y 4202496
#define WS_O 8396800
#define WS_S 8921088

static __device__ __forceinline__ unsigned short f2bf(float f) {
  unsigned int u = __builtin_bit_cast(unsigned int, f);
  u += 0x7fffu + ((u >> 16) & 1u);
  return (unsigned short)(u >> 16);
}
static __device__ __forceinline__ float bf2f(unsigned short s) {
  return __builtin_bit_cast(float, ((unsigned int)s) << 16);
}

// ================= K0: C[m][mm] = SCALE * sum_n bf(Wspec_q[m][n])*bf(Wspec_k[mm][n]) =================
__global__ __launch_bounds__(512)
void k0_cmat(const float* __restrict__ Wspec, char* __restrict__ Cws) {
  const int t = threadIdx.x;
  const int m = t >> 3, mm0 = (t & 7) * 8;
  float qv[64];
  #pragma unroll 8
  for (int n = 0; n < 64; ++n) qv[n] = bf2f(f2bf(Wspec[m * 192 + n]));
  float accC[8];
  #pragma unroll
  for (int j = 0; j < 8; ++j) {
    const float* kr = Wspec + (mm0 + j) * 192 + 64;
    float a = 0.f;
    #pragma unroll 8
    for (int n = 0; n < 64; ++n) a = fmaf(qv[n], bf2f(f2bf(kr[n])), a);
    accC[j] = a;
  }
  uint4 pk;
  pk.x = (unsigned)f2bf(accC[0] * SCALE) | ((unsigned)f2bf(accC[1] * SCALE) << 16);
  pk.y = (unsigned)f2bf(accC[2] * SCALE) | ((unsigned)f2bf(accC[3] * SCALE) << 16);
  pk.z = (unsigned)f2bf(accC[4] * SCALE) | ((unsigned)f2bf(accC[5] * SCALE) << 16);
  pk.w = (unsigned)f2bf(accC[6] * SCALE) | ((unsigned)f2bf(accC[7] * SCALE) << 16);
  *(uint4*)(Cws + m * 128 + ((mm0 * 2) ^ ((m & 7) << 4))) = pk;
}

// ================= K1: QC = XC@Wq (per-head cols), U_h = QC_h @ Wkv_k_h^T =================
// grid 32: (bt = blk>>3, h = blk&7). 512 threads: br = t>>3 (row), c8 = (t&7)*8 (col8).
__global__ __launch_bounds__(512)
void k1_qc_u(const float* __restrict__ x, const float* __restrict__ Wq,
             const float* __restrict__ Wkv, float* __restrict__ Uw) {
  __shared__ float bv[64 * 76];  // vector operand [row][col], pad 76
  __shared__ float bw[64 * 67];  // weight operand [row][col], pad 67
  const int t = threadIdx.x;
  const int br = t >> 3, c8 = (t & 7) * 8;
  const int bt = blockIdx.x >> 3, h = blockIdx.x & 7;
  const int B0 = bt * 64;

  // ---- stage 1: QC_tile[b][j] = sum_d XC[b][d] * Wq[d][h*64+j] ----
  float acc[8] = {0.f, 0.f, 0.f, 0.f, 0.f, 0.f, 0.f, 0.f};
  for (int dblk = 0; dblk < 8; ++dblk) {
    {
      const float* s = x + (((size_t)(B0 + br)) * 64 + 32) * 512 + dblk * 64 + c8;
      float4 a = *(const float4*)s, bq = *(const float4*)(s + 4);
      *(float4*)(bv + br * 76 + c8) = a;
      *(float4*)(bv + br * 76 + c8 + 4) = bq;
    }
    {
      const float* s = Wq + (size_t)(dblk * 64 + br) * 512 + h * 64 + c8;
      float4 a = *(const float4*)s, bq = *(const float4*)(s + 4);
      float* d = bw + br * 67 + c8;
      d[0] = a.x; d[1] = a.y; d[2] = a.z; d[3] = a.w;
      d[4] = bq.x; d[5] = bq.y; d[6] = bq.z; d[7] = bq.w;
    }
    __syncthreads();
    #pragma unroll 4
    for (int d4 = 0; d4 < 16; ++d4) {
      float4 xv = *(const float4*)(bv + br * 76 + d4 * 4);
      float xs[4] = {xv.x, xv.y, xv.z, xv.w};
      #pragma unroll
      for (int k = 0; k < 4; ++k) {
        const float* wr = bw + (d4 * 4 + k) * 67 + c8;
        #pragma unroll
        for (int j = 0; j < 8; ++j) acc[j] = fmaf(xs[k], wr[j], acc[j]);
      }
    }
    __syncthreads();
  }
  // QC tile -> bv
  {
    float* d = bv + br * 76 + c8;
    #pragma unroll
    for (int j = 0; j < 8; ++j) d[j] = acc[j];
  }
  __syncthreads();

  // ---- stage 2: U[b][h][dout] = sum_jj QC[b][jj] * Wkv[dout][h*64+jj] ----
  for (int dblk = 0; dblk < 8; ++dblk) {
    {
      const float* s = Wkv + (size_t)(dblk * 64 + br) * 1024 + h * 64 + c8;
      float4 a = *(const float4*)s, bq = *(const float4*)(s + 4);
      float* d = bw + br * 67 + c8;
      d[0] = a.x; d[1] = a.y; d[2] = a.z; d[3] = a.w;
      d[4] = bq.x; d[5] = bq.y; d[6] = bq.z; d[7] = bq.w;
    }
    __syncthreads();
    float acc2[8] = {0.f, 0.f, 0.f, 0.f, 0.f, 0.f, 0.f, 0.f};
    #pragma unroll 4
    for (int j4 = 0; j4 < 16; ++j4) {
      float4 qv = *(const float4*)(bv + br * 76 + j4 * 4);
      float qs[4] = {qv.x, qv.y, qv.z, qv.w};
      #pragma unroll
      for (int k = 0; k < 4; ++k) {
        #pragma unroll
        for (int dd = 0; dd < 8; ++dd)
          acc2[dd] = fmaf(qs[k], bw[(c8 + dd) * 67 + j4 * 4 + k], acc2[dd]);
      }
    }
    float* ud = Uw + (((size_t)(B0 + br)) * 8 + h) * 512 + dblk * 64 + c8;
    #pragma unroll
    for (int dd = 0; dd < 8; ++dd) ud[dd] = acc2[dd];
    __syncthreads();
  }
}

// ================= K2: batch-local spatial attention (scores, softmax, y) =================
__global__ __launch_bounds__(512)
void k2_attn(const float* __restrict__ x, const float* __restrict__ Uw,
             float* __restrict__ Yw) {
  __shared__ float ul[8 * 512];
  __shared__ float scoreL[8 * 64];
  __shared__ float pT[64 * 8];
  const int t = threadIdx.x;
  const int lane = t & 63;
  const int wave = t >> 6;
  const int b = blockIdx.x;
  const float* xb = x + (size_t)b * NP * DIM;

  #pragma unroll
  for (int k = 0; k < 8; ++k) ul[t + k * 512] = Uw[(size_t)b * 4096 + t + k * 512];
  __syncthreads();

  // scores[h][m] = sum_d x[m][d]*u[h][d] ; wave owns m in [wave*8, wave*8+8)
  {
    float4 uf0[8], uf1[8];
    #pragma unroll
    for (int h = 0; h < 8; ++h) {
      uf0[h] = *(const float4*)(ul + h * 512 + 4 * lane);
      uf1[h] = *(const float4*)(ul + h * 512 + 256 + 4 * lane);
    }
    #pragma unroll 2
    for (int i = 0; i < 8; ++i) {
      const int m = wave * 8 + i;
      const float4* xr = (const float4*)(xb + (size_t)m * DIM);
      float4 xv0 = xr[lane];
      float4 xv1 = xr[64 + lane];
      #pragma unroll
      for (int h = 0; h < 8; ++h) {
        float p = xv0.x*uf0[h].x + xv0.y*uf0[h].y + xv0.z*uf0[h].z + xv0.w*uf0[h].w
                + xv1.x*uf1[h].x + xv1.y*uf1[h].y + xv1.z*uf1[h].z + xv1.w*uf1[h].w;
        p += __shfl_xor(p, 1);
        p += __shfl_xor(p, 2);
        p += __shfl_xor(p, 4);
        p += __shfl_xor(p, 8);
        p += __shfl_xor(p, 16);
        p += __shfl_xor(p, 32);
        if (lane == 0) scoreL[h * 64 + m] = p;
      }
    }
  }
  __syncthreads();

  // per-head softmax (wave = h, lane = m)
  {
    float sc = scoreL[wave * 64 + lane] * SCALE;
    float mx = sc;
    #pragma unroll
    for (int off = 32; off > 0; off >>= 1)
      mx = fmaxf(mx, __shfl_xor(mx, off));
    float ev = __expf(sc - mx);
    float sm = ev;
    #pragma unroll
    for (int off = 32; off > 0; off >>= 1)
      sm += __shfl_xor(sm, off);
    pT[lane * NH + wave] = ev / sm;
  }
  __syncthreads();

  // y[h][d] = sum_m p[h][m]*x[m][d], d = t
  {
    float acc[NH];
    #pragma unroll
    for (int h = 0; h < NH; ++h) acc[h] = 0.f;
    #pragma unroll 2
    for (int m = 0; m < NP; ++m) {
      float xv = xb[(size_t)m * DIM + t];
      const float4* pp = (const float4*)(pT + m * NH);
      float4 p0 = pp[0], p1 = pp[1];
      acc[0] = fmaf(p0.x, xv, acc[0]);
      acc[1] = fmaf(p0.y, xv, acc[1]);
      acc[2] = fmaf(p0.z, xv, acc[2]);
      acc[3] = fmaf(p0.w, xv, acc[3]);
      acc[4] = fmaf(p1.x, xv, acc[4]);
      acc[5] = fmaf(p1.y, xv, acc[5]);
      acc[6] = fmaf(p1.z, xv, acc[6]);
      acc[7] = fmaf(p1.w, xv, acc[7]);
    }
    #pragma unroll
    for (int h = 0; h < NH; ++h)
      Yw[(((size_t)b) * 8 + h) * 512 + t] = acc[h];
  }
}

// ================= K3a: O[b][h*64+j] = sum_d Y[b][h][d] * Wkv[d][512+h*64+j] =================
__global__ __launch_bounds__(512)
void k3a_o(const float* __restrict__ Yw, const float* __restrict__ Wkv,
           float* __restrict__ Ow) {
  __shared__ float bv[64 * 76];
  __shared__ float bw[64 * 67];
  const int t = threadIdx.x;
  const int br = t >> 3, c8 = (t & 7) * 8;
  const int bt = blockIdx.x >> 3, h = blockIdx.x & 7;
  const int B0 = bt * 64;

  float acc[8] = {0.f, 0.f, 0.f, 0.f, 0.f, 0.f, 0.f, 0.f};
  for (int dblk = 0; dblk < 8; ++dblk) {
    {
      const float* s = Yw + (((size_t)(B0 + br)) * 8 + h) * 512 + dblk * 64 + c8;
      float4 a = *(const float4*)s, bq = *(const float4*)(s + 4);
      *(float4*)(bv + br * 76 + c8) = a;
      *(float4*)(bv + br * 76 + c8 + 4) = bq;
    }
    {
      const float* s = Wkv + (size_t)(dblk * 64 + br) * 1024 + 512 + h * 64 + c8;
      float4 a = *(const float4*)s, bq = *(const float4*)(s + 4);
      float* d = bw + br * 67 + c8;
      d[0] = a.x; d[1] = a.y; d[2] = a.z; d[3] = a.w;
      d[4] = bq.x; d[5] = bq.y; d[6] = bq.z; d[7] = bq.w;
    }
    __syncthreads();
    #pragma unroll 4
    for (int d4 = 0; d4 < 16; ++d4) {
      float4 yv = *(const float4*)(bv + br * 76 + d4 * 4);
      float ys[4] = {yv.x, yv.y, yv.z, yv.w};
      #pragma unroll
      for (int k = 0; k < 4; ++k) {
        const float* wr = bw + (d4 * 4 + k) * 67 + c8;
        #pragma unroll
        for (int j = 0; j < 8; ++j) acc[j] = fmaf(ys[k], wr[j], acc[j]);
      }
    }
    __syncthreads();
  }
  float* od = Ow + ((size_t)(B0 + br)) * 512 + h * 64 + c8;
  #pragma unroll
  for (int j = 0; j < 8; ++j) od[j] = acc[j];
}

// ================= K3b: S[b][e] = bout[e] + sum_j O[b][j] * Wout[j][e] =================
__global__ __launch_bounds__(512)
void k3b_s(const float* __restrict__ Ow, const float* __restrict__ Wout,
           const float* __restrict__ bout, float* __restrict__ Sw) {
  __shared__ float bv[64 * 76];
  __shared__ float bw[64 * 67];
  const int t = threadIdx.x;
  const int br = t >> 3, c8 = (t & 7) * 8;
  const int bt = blockIdx.x >> 3, et = blockIdx.x & 7;
  const int B0 = bt * 64, e0 = et * 64;

  float acc[8] = {0.f, 0.f, 0.f, 0.f, 0.f, 0.f, 0.f, 0.f};
  for (int jblk = 0; jblk < 8; ++jblk) {
    {
      const float* s = Ow + ((size_t)(B0 + br)) * 512 + jblk * 64 + c8;
      float4 a = *(const float4*)s, bq = *(const float4*)(s + 4);
      *(float4*)(bv + br * 76 + c8) = a;
      *(float4*)(bv + br * 76 + c8 + 4) = bq;
    }
    {
      const float* s = Wout + (size_t)(jblk * 64 + br) * 512 + e0 + c8;
      float4 a = *(const float4*)s, bq = *(const float4*)(s + 4);
      float* d = bw + br * 67 + c8;
      d[0] = a.x; d[1] = a.y; d[2] = a.z; d[3] = a.w;
      d[4] = bq.x; d[5] = bq.y; d[6] = bq.z; d[7] = bq.w;
    }
    __syncthreads();
    #pragma unroll 4
    for (int j4 = 0; j4 < 16; ++j4) {
      float4 ov = *(const float4*)(bv + br * 76 + j4 * 4);
      float os[4] = {ov.x, ov.y, ov.z, ov.w};
      #pragma unroll
      for (int k = 0; k < 4; ++k) {
        const float* wr = bw + (j4 * 4 + k) * 67 + c8;
        #pragma unroll
        for (int j = 0; j < 8; ++j) acc[j] = fmaf(os[k], wr[j], acc[j]);
      }
    }
    __syncthreads();
  }
  float* sd = Sw + ((size_t)(B0 + br)) * 512 + e0 + c8;
  #pragma unroll
  for (int j = 0; j < 8; ++j) sd[j] = acc[j] + bout[e0 + c8 + j];
}

// ================= K4: spectral phase (W2-MFMA + z-MFMA + softmax + out) =================
// LDS: XT [0,65536) ; W2T [65536,131072) ; C [131072,139264) ; SL [139264,141312)
#define K4_LDS 141312

__global__ __launch_bounds__(512, 2)
void k4_spec(const float* __restrict__ x, const char* __restrict__ Cws,
             const float* __restrict__ Sw, float* __restrict__ out) {
  extern __shared__ char smem[];
  char* xTc  = smem;
  char* w2Tc = smem + 65536;
  char* Cc   = smem + 131072;
  float* s_l = (float*)(smem + 139264);

  const int t = threadIdx.x;
  const int lane = t & 63;
  const int wave = t >> 6;
  const int b = blockIdx.x;
  const float* xb = x + (size_t)b * NP * DIM;

  const int lo_off = ((lane & 15) * 128) + ((((lane >> 4) * 16)     ) ^ ((lane & 7) << 4));
  const int hi_off = ((lane & 15) * 128) + ((((lane >> 4) * 16) + 64) ^ ((lane & 7) << 4));

  // stage xT (bf16, swizzled), C, s_l
  {
    const int d = t;
    #pragma unroll
    for (int c = 0; c < 8; ++c) {
      float v0 = xb[(c * 8 + 0) * DIM + d];
      float v1 = xb[(c * 8 + 1) * DIM + d];
      float v2 = xb[(c * 8 + 2) * DIM + d];
      float v3 = xb[(c * 8 + 3) * DIM + d];
      float v4 = xb[(c * 8 + 4) * DIM + d];
      float v5 = xb[(c * 8 + 5) * DIM + d];
      float v6 = xb[(c * 8 + 6) * DIM + d];
      float v7 = xb[(c * 8 + 7) * DIM + d];
      uint4 pk;
      pk.x = (unsigned)f2bf(v0) | ((unsigned)f2bf(v1) << 16);
      pk.y = (unsigned)f2bf(v2) | ((unsigned)f2bf(v3) << 16);
      pk.z = (unsigned)f2bf(v4) | ((unsigned)f2bf(v5) << 16);
      pk.w = (unsigned)f2bf(v6) | ((unsigned)f2bf(v7) << 16);
      *(uint4*)(xTc + d * 128 + ((c * 16) ^ ((d & 7) << 4))) = pk;
    }
    ((uint4*)Cc)[t] = ((const uint4*)Cws)[t];
    s_l[t] = Sw[(size_t)b * 512 + t];
  }
  __syncthreads();

  // W2-MFMA: W2[m][e] = sum_mm C[m][mm] * x[mm][e]; write w2T[e][m] bf16 swizzled
  {
    bf16x8 af0[4], af1[4];
    #pragma unroll
    for (int mt = 0; mt < 4; ++mt) {
      af0[mt] = *(const bf16x8*)(Cc + mt * 16 * 128 + lo_off);
      af1[mt] = *(const bf16x8*)(Cc + mt * 16 * 128 + hi_off);
    }
    #pragma unroll
    for (int etl = 0; etl < 4; ++etl) {
      const int e0 = (wave * 4 + etl) * 16;
      bf16x8 b0 = *(const bf16x8*)(xTc + e0 * 128 + lo_off);
      bf16x8 b1 = *(const bf16x8*)(xTc + e0 * 128 + hi_off);
      #pragma unroll
      for (int mt = 0; mt < 4; ++mt) {
        f32x4 c = {0.f, 0.f, 0.f, 0.f};
        c = __builtin_amdgcn_mfma_f32_16x16x32_bf16(af0[mt], b0, c, 0, 0, 0);
        c = __builtin_amdgcn_mfma_f32_16x16x32_bf16(af1[mt], b1, c, 0, 0, 0);
        const int e = e0 + (lane & 15);
        const int mrow = mt * 16 + (lane >> 4) * 4;
        uint2 pk;
        pk.x = (unsigned)f2bf(c[0]) | ((unsigned)f2bf(c[1]) << 16);
        pk.y = (unsigned)f2bf(c[2]) | ((unsigned)f2bf(c[3]) << 16);
        *(uint2*)(w2Tc + e * 128 + ((mrow * 2) ^ ((e & 7) << 4))) = pk;
      }
    }
  }
  __syncthreads();

  // z = xT' * W2 via MFMA; softmax (no max subtraction; |z| small); t accumulation
  float treg[32];
  #pragma unroll
  for (int et = 0; et < 32; ++et) treg[et] = 0.f;

  for (int pass = 0; pass < 4; ++pass) {
    const int d0 = pass * 128 + wave * 16;
    bf16x8 a0 = *(const bf16x8*)(xTc + d0 * 128 + lo_off);
    bf16x8 a1 = *(const bf16x8*)(xTc + d0 * 128 + hi_off);
    f32x4 acc[32];
    #pragma unroll
    for (int et = 0; et < 32; ++et) {
      bf16x8 b0 = *(const bf16x8*)(w2Tc + et * 2048 + lo_off);
      bf16x8 b1 = *(const bf16x8*)(w2Tc + et * 2048 + hi_off);
      f32x4 c = {0.f, 0.f, 0.f, 0.f};
      c = __builtin_amdgcn_mfma_f32_16x16x32_bf16(a0, b0, c, 0, 0, 0);
      c = __builtin_amdgcn_mfma_f32_16x16x32_bf16(a1, b1, c, 0, 0, 0);
      acc[et] = c;
    }
    float rs[4] = {0.f, 0.f, 0.f, 0.f};
    #pragma unroll
    for (int et = 0; et < 32; ++et) {
      #pragma unroll
      for (int r = 0; r < 4; ++r) {
        float ev = __expf(acc[et][r]);
        acc[et][r] = ev;
        rs[r] += ev;
      }
    }
    #pragma unroll
    for (int r = 0; r < 4; ++r) {
      rs[r] += __shfl_xor(rs[r], 1);
      rs[r] += __shfl_xor(rs[r], 2);
      rs[r] += __shfl_xor(rs[r], 4);
      rs[r] += __shfl_xor(rs[r], 8);
    }
    float coef[4];
    #pragma unroll
    for (int r = 0; r < 4; ++r)
      coef[r] = s_l[d0 + (lane >> 4) * 4 + r] / rs[r];
    #pragma unroll
    for (int et = 0; et < 32; ++et) {
      float tp = treg[et];
      tp = fmaf(coef[0], acc[et][0], tp);
      tp = fmaf(coef[1], acc[et][1], tp);
      tp = fmaf(coef[2], acc[et][2], tp);
      tp = fmaf(coef[3], acc[et][3], tp);
      treg[et] = tp;
    }
  }
  __syncthreads();  // done reading xT/w2T; xT region becomes partial buffer

  #pragma unroll
  for (int et = 0; et < 32; ++et) {
    treg[et] += __shfl_xor(treg[et], 16);
    treg[et] += __shfl_xor(treg[et], 32);
  }
  float* wpart = (float*)xTc;  // [8][512]
  if (lane < 16) {
    #pragma unroll
    for (int et = 0; et < 32; ++et)
      wpart[wave * 512 + et * 16 + lane] = treg[et];
  }
  __syncthreads();

  float tf = 0.f;
  #pragma unroll
  for (int w = 0; w < 8; ++w) tf += wpart[w * 512 + t];

  float* ob = out + (size_t)b * NP * DIM + t;
  #pragma unroll 4
  for (int n = 0; n < NP; ++n) ob[n * DIM] = tf;
}

extern "C" void kernel_launch(void* const* d_in, const int* in_sizes, int n_in,
                              void* d_out, int out_size, void* d_ws, size_t ws_size,
                              hipStream_t stream) {
  (void)in_sizes; (void)n_in; (void)out_size; (void)ws_size;
  const float* x     = (const float*)d_in[0];
  const float* Wq    = (const float*)d_in[1];
  const float* Wkv   = (const float*)d_in[2];
  const float* Wout  = (const float*)d_in[3];
  const float* bout  = (const float*)d_in[4];
  const float* Wspec = (const float*)d_in[5];
  float* out = (float*)d_out;

  char* ws = (char*)d_ws;
  char*  Cws = ws + WS_C;
  float* Uw  = (float*)(ws + WS_U);
  float* Yw  = (float*)(ws + WS_Y);
  float* Ow  = (float*)(ws + WS_O);
  float* Sw  = (float*)(ws + WS_S);

  hipFuncSetAttribute(reinterpret_cast<const void*>(k4_spec),
                      hipFuncAttributeMaxDynamicSharedMemorySize, K4_LDS);

  k0_cmat<<<dim3(1),   dim3(512), 0, stream>>>(Wspec, Cws);
  k1_qc_u<<<dim3(32),  dim3(512), 0, stream>>>(x, Wq, Wkv, Uw);
  k2_attn<<<dim3(256), dim3(512), 0, stream>>>(x, Uw, Yw);
  k3a_o  <<<dim3(32),  dim3(512), 0, stream>>>(Yw, Wkv, Ow);
  k3b_s  <<<dim3(32),  dim3(512), 0, stream>>>(Ow, Wout, bout, Sw);
  k4_spec<<<dim3(256), dim3(512), K4_LDS, stream>>>(x, Cws, Sw, out);
}

// Round 6
// 197.995 us; speedup vs baseline: 2.0752x; 2.0752x over previous
//
#include <hip/hip_runtime.h>

#define NP 64
#define DIM 512
#define NH 8
#define SCALE 0.125f

typedef __attribute__((ext_vector_type(4))) float f32x4;
typedef __attribute__((ext_vector_type(8))) short bf16x8;

// ---------------- workspace layout (bytes), total ~12.6 MB ----------------
#define WS_C   0                 // bf16 C[64][64] swizzled (8 KB)
#define WS_MT  8192              // bf16 Mt[4096 n=(h,e)][512 k=d]   (4 MB)
#define WS_PT  4202496           // bf16 Pt[512 e][4096 K=(h,d)]    (4 MB)
#define WS_U   8396800           // bf16 U[256 b][4096 n=(h,e)]     (2 MB)
#define WS_Y   10493952          // bf16 Y[256 b][4096 K=(h,d)]     (2 MB)
#define WS_S   12591104          // f32  S[256 b][512 e]            (512 KB)

static __device__ __forceinline__ unsigned short f2bf(float f) {
  unsigned int u = __builtin_bit_cast(unsigned int, f);
  u += 0x7fffu + ((u >> 16) & 1u);
  return (unsigned short)(u >> 16);
}
static __device__ __forceinline__ float bf2f(unsigned short s) {
  return __builtin_bit_cast(float, ((unsigned int)s) << 16);
}
static __device__ __forceinline__ unsigned pk2(float a, float b) {
  return (unsigned)f2bf(a) | ((unsigned)f2bf(b) << 16);
}

// ================= KW: batch-independent precompute =================
// blocks 0..511   : Mt[h*512+e][d] = sum_j Wq[d][h*64+j]*Wkv[e][h*64+j]
// blocks 512..1023: Pt[e][h*512+d] = sum_j Wkv[d][512+h*64+j]*Wout[h*64+j][e]
// block 1024      : C[m][mm] = SCALE*sum_n Wspec[m][n]*Wspec[mm][64+n] (swizzled bf16)
__global__ __launch_bounds__(512)
void kw_prep(const float* __restrict__ Wq, const float* __restrict__ Wkv,
             const float* __restrict__ Wout, const float* __restrict__ Wspec,
             char* __restrict__ ws) {
  __shared__ float wa[64 * 65];
  __shared__ float wb[64 * 65];
  const int t = threadIdx.x;
  const int blk = blockIdx.x;
  const int sr = t >> 3, sc8 = (t & 7) * 8;

  if (blk == 1024) {
    #pragma unroll
    for (int cc = 0; cc < 8; ++cc) {
      wa[sr * 65 + sc8 + cc] = Wspec[sr * 192 + sc8 + cc];
      wb[sr * 65 + sc8 + cc] = Wspec[sr * 192 + 64 + sc8 + cc];
    }
    __syncthreads();
    const int m = sr, mm0 = sc8;
    float acc[8] = {0.f, 0.f, 0.f, 0.f, 0.f, 0.f, 0.f, 0.f};
    for (int n = 0; n < 64; ++n) {
      float qv = wa[m * 65 + n];
      #pragma unroll
      for (int j = 0; j < 8; ++j)
        acc[j] = fmaf(qv, wb[(mm0 + j) * 65 + n], acc[j]);
    }
    uint4 pk;
    pk.x = pk2(acc[0] * SCALE, acc[1] * SCALE);
    pk.y = pk2(acc[2] * SCALE, acc[3] * SCALE);
    pk.z = pk2(acc[4] * SCALE, acc[5] * SCALE);
    pk.w = pk2(acc[6] * SCALE, acc[7] * SCALE);
    *(uint4*)(ws + WS_C + m * 128 + ((mm0 * 2) ^ ((m & 7) << 4))) = pk;
    return;
  }

  const bool isP = blk >= 512;
  const int id = blk & 511;
  const int h = id >> 6, et = (id >> 3) & 7, dt = id & 7;

  const float* sa = isP ? (Wkv + (size_t)(dt * 64 + sr) * 1024 + 512 + h * 64)
                        : (Wq + (size_t)(dt * 64 + sr) * 512 + h * 64);
  const float* sb = isP ? (Wout + (size_t)(h * 64 + sr) * 512 + et * 64)
                        : (Wkv + (size_t)(et * 64 + sr) * 1024 + h * 64);
  {
    float4 a0 = *(const float4*)(sa + sc8), a1 = *(const float4*)(sa + sc8 + 4);
    float* d = wa + sr * 65 + sc8;
    d[0] = a0.x; d[1] = a0.y; d[2] = a0.z; d[3] = a0.w;
    d[4] = a1.x; d[5] = a1.y; d[6] = a1.z; d[7] = a1.w;
    float4 b0 = *(const float4*)(sb + sc8), b1 = *(const float4*)(sb + sc8 + 4);
    float* e = wb + sr * 65 + sc8;
    e[0] = b0.x; e[1] = b0.y; e[2] = b0.z; e[3] = b0.w;
    e[4] = b1.x; e[5] = b1.y; e[6] = b1.z; e[7] = b1.w;
  }
  __syncthreads();

  const int er = sr, dc8 = sc8;
  float acc[8] = {0.f, 0.f, 0.f, 0.f, 0.f, 0.f, 0.f, 0.f};
  if (!isP) {
    for (int j = 0; j < 64; ++j) {
      float bv = wb[er * 65 + j];   // Wkv[e][j]
      #pragma unroll
      for (int dd = 0; dd < 8; ++dd)
        acc[dd] = fmaf(bv, wa[(dc8 + dd) * 65 + j], acc[dd]);
    }
  } else {
    for (int j = 0; j < 64; ++j) {
      float bv = wb[j * 65 + er];   // Wout[j][e]
      #pragma unroll
      for (int dd = 0; dd < 8; ++dd)
        acc[dd] = fmaf(bv, wa[(dc8 + dd) * 65 + j], acc[dd]);
    }
  }
  uint4 pk;
  pk.x = pk2(acc[0], acc[1]);
  pk.y = pk2(acc[2], acc[3]);
  pk.z = pk2(acc[4], acc[5]);
  pk.w = pk2(acc[6], acc[7]);
  if (!isP)
    *(uint4*)(ws + WS_MT + ((size_t)(h * 512 + et * 64 + er) * 512 + dt * 64 + dc8) * 2) = pk;
  else
    *(uint4*)(ws + WS_PT + ((size_t)(et * 64 + er) * 4096 + h * 512 + dt * 64 + dc8) * 2) = pk;
}

// ================= KU: U[256][4096] = XC[256][512] @ Mt^T (bf16 MFMA) =================
#define GEMM_LDS 131072
__global__ __launch_bounds__(512, 2)
void ku_u(const float* __restrict__ x, const char* __restrict__ ws,
          char* __restrict__ ws_u) {
  extern __shared__ char sm[];
  char* At = sm;            // [8 kc][64 r][128 B], swizzled
  char* Bt = sm + 65536;
  const int t = threadIdx.x, lane = t & 63, wave = t >> 6;
  const int bt = blockIdx.x >> 6, nt = blockIdx.x & 63;
  const int b0 = bt * 64, n0 = nt * 64;
  const char* Mt = ws + WS_MT;

  // stage A: center rows f32 -> bf16, swizzled k-major subtiles
  #pragma unroll
  for (int i = 0; i < 8; ++i) {
    const int r = wave * 8 + i;
    const float4* xr = (const float4*)(x + ((size_t)(b0 + r) * 64 + 32) * 512);
    float4 a = xr[lane], c = xr[64 + lane];
    uint2 pa = {pk2(a.x, a.y), pk2(a.z, a.w)};
    uint2 pc = {pk2(c.x, c.y), pk2(c.z, c.w)};
    const int swz = (r & 7) << 4;
    const int byt = (8 * (lane & 15)) ^ swz;
    *(uint2*)(At + (lane >> 4) * 8192 + r * 128 + byt) = pa;
    *(uint2*)(At + (4 + (lane >> 4)) * 8192 + r * 128 + byt) = pc;
  }
  // stage B from Mt rows (bf16, contiguous 1 KB/row)
  #pragma unroll
  for (int i = 0; i < 8; ++i) {
    const int r = wave * 8 + i;
    uint4 v = ((const uint4*)(Mt + (size_t)(n0 + r) * 1024))[lane];
    *(uint4*)(Bt + (lane >> 3) * 8192 + r * 128 + ((16 * (lane & 7)) ^ ((r & 7) << 4))) = v;
  }
  __syncthreads();

  const int lo = ((lane & 15) * 128) + (((lane >> 4) * 16) ^ ((lane & 7) << 4));
  const int hi = ((lane & 15) * 128) + ((((lane >> 4) * 16) + 64) ^ ((lane & 7) << 4));
  const int bsub = wave & 3, npair = wave >> 2;

  f32x4 c0 = {0.f, 0.f, 0.f, 0.f}, c1 = {0.f, 0.f, 0.f, 0.f};
  #pragma unroll
  for (int kc = 0; kc < 8; ++kc) {
    const char* ab = At + kc * 8192 + bsub * 2048;
    bf16x8 aL = *(const bf16x8*)(ab + lo);
    bf16x8 aH = *(const bf16x8*)(ab + hi);
    const char* bb0 = Bt + kc * 8192 + (npair * 2) * 2048;
    const char* bb1 = bb0 + 2048;
    c0 = __builtin_amdgcn_mfma_f32_16x16x32_bf16(aL, *(const bf16x8*)(bb0 + lo), c0, 0, 0, 0);
    c0 = __builtin_amdgcn_mfma_f32_16x16x32_bf16(aH, *(const bf16x8*)(bb0 + hi), c0, 0, 0, 0);
    c1 = __builtin_amdgcn_mfma_f32_16x16x32_bf16(aL, *(const bf16x8*)(bb1 + lo), c1, 0, 0, 0);
    c1 = __builtin_amdgcn_mfma_f32_16x16x32_bf16(aH, *(const bf16x8*)(bb1 + hi), c1, 0, 0, 0);
  }
  unsigned short* U = (unsigned short*)ws_u;
  const int brow = b0 + bsub * 16 + (lane >> 4) * 4;
  const int nc0 = n0 + (npair * 2) * 16 + (lane & 15);
  #pragma unroll
  for (int r = 0; r < 4; ++r) {
    U[(size_t)(brow + r) * 4096 + nc0] = f2bf(c0[r]);
    U[(size_t)(brow + r) * 4096 + nc0 + 16] = f2bf(c1[r]);
  }
}

// ================= K2: batch-local spatial attention =================
__global__ __launch_bounds__(512)
void k2_attn(const float* __restrict__ x, const char* __restrict__ ws_u,
             char* __restrict__ ws_y) {
  __shared__ float ul[8 * 512];
  __shared__ float scoreL[8 * 64];
  __shared__ float pT[64 * 8];
  const int t = threadIdx.x;
  const int lane = t & 63;
  const int wave = t >> 6;
  const int b = blockIdx.x;
  const float* xb = x + (size_t)b * NP * DIM;

  {
    uint4 v = ((const uint4*)(ws_u + (size_t)b * 8192))[t];
    const unsigned short* pv = (const unsigned short*)&v;
    float* d = ul + t * 8;
    #pragma unroll
    for (int g = 0; g < 8; ++g) d[g] = bf2f(pv[g]);
  }
  __syncthreads();

  // scores[h][m] = sum_d x[m][d]*u[h][d]; wave owns m in [wave*8, wave*8+8)
  {
    float4 uf0[8], uf1[8];
    #pragma unroll
    for (int h = 0; h < 8; ++h) {
      uf0[h] = *(const float4*)(ul + h * 512 + 4 * lane);
      uf1[h] = *(const float4*)(ul + h * 512 + 256 + 4 * lane);
    }
    #pragma unroll 2
    for (int i = 0; i < 8; ++i) {
      const int m = wave * 8 + i;
      const float4* xr = (const float4*)(xb + (size_t)m * DIM);
      float4 xv0 = xr[lane];
      float4 xv1 = xr[64 + lane];
      #pragma unroll
      for (int h = 0; h < 8; ++h) {
        float p = xv0.x * uf0[h].x + xv0.y * uf0[h].y + xv0.z * uf0[h].z + xv0.w * uf0[h].w
                + xv1.x * uf1[h].x + xv1.y * uf1[h].y + xv1.z * uf1[h].z + xv1.w * uf1[h].w;
        p += __shfl_xor(p, 1);
        p += __shfl_xor(p, 2);
        p += __shfl_xor(p, 4);
        p += __shfl_xor(p, 8);
        p += __shfl_xor(p, 16);
        p += __shfl_xor(p, 32);
        if (lane == 0) scoreL[h * 64 + m] = p;
      }
    }
  }
  __syncthreads();

  {
    float sc = scoreL[wave * 64 + lane] * SCALE;
    float mx = sc;
    #pragma unroll
    for (int off = 32; off > 0; off >>= 1)
      mx = fmaxf(mx, __shfl_xor(mx, off));
    float ev = __expf(sc - mx);
    float sm = ev;
    #pragma unroll
    for (int off = 32; off > 0; off >>= 1)
      sm += __shfl_xor(sm, off);
    pT[lane * NH + wave] = ev / sm;
  }
  __syncthreads();

  {
    float acc[NH];
    #pragma unroll
    for (int h = 0; h < NH; ++h) acc[h] = 0.f;
    #pragma unroll 2
    for (int m = 0; m < NP; ++m) {
      float xv = xb[(size_t)m * DIM + t];
      const float4* pp = (const float4*)(pT + m * NH);
      float4 p0 = pp[0], p1 = pp[1];
      acc[0] = fmaf(p0.x, xv, acc[0]);
      acc[1] = fmaf(p0.y, xv, acc[1]);
      acc[2] = fmaf(p0.z, xv, acc[2]);
      acc[3] = fmaf(p0.w, xv, acc[3]);
      acc[4] = fmaf(p1.x, xv, acc[4]);
      acc[5] = fmaf(p1.y, xv, acc[5]);
      acc[6] = fmaf(p1.z, xv, acc[6]);
      acc[7] = fmaf(p1.w, xv, acc[7]);
    }
    unsigned short* Y = (unsigned short*)ws_y;
    #pragma unroll
    for (int h = 0; h < NH; ++h)
      Y[(size_t)b * 4096 + h * 512 + t] = f2bf(acc[h]);
  }
}

// ================= KS: S[256][512] = Ycat[256][4096] @ Pt^T + bout (bf16 MFMA) =================
__global__ __launch_bounds__(512, 2)
void ks_s(const char* __restrict__ ws_y, const char* __restrict__ ws,
          const float* __restrict__ bout, float* __restrict__ Sw) {
  extern __shared__ char sm[];
  char* At = sm;
  char* Bt = sm + 65536;
  const int t = threadIdx.x, lane = t & 63, wave = t >> 6;
  const int bt = blockIdx.x >> 3, et = blockIdx.x & 7;
  const int b0 = bt * 64, e0 = et * 64;
  const char* Pt = ws + WS_PT;

  const int lo = ((lane & 15) * 128) + (((lane >> 4) * 16) ^ ((lane & 7) << 4));
  const int hi = ((lane & 15) * 128) + ((((lane >> 4) * 16) + 64) ^ ((lane & 7) << 4));
  const int bsub = wave & 3, epair = wave >> 2;

  f32x4 c0 = {0.f, 0.f, 0.f, 0.f}, c1 = {0.f, 0.f, 0.f, 0.f};
  for (int it = 0; it < 8; ++it) {
    const size_t kb2 = (size_t)it * 1024;  // byte offset of k-chunk (512 bf16)
    #pragma unroll
    for (int i = 0; i < 8; ++i) {
      const int r = wave * 8 + i;
      const int byt = (16 * (lane & 7)) ^ ((r & 7) << 4);
      uint4 va = ((const uint4*)(ws_y + (size_t)(b0 + r) * 8192 + kb2))[lane];
      *(uint4*)(At + (lane >> 3) * 8192 + r * 128 + byt) = va;
      uint4 vb = ((const uint4*)(Pt + (size_t)(e0 + r) * 8192 + kb2))[lane];
      *(uint4*)(Bt + (lane >> 3) * 8192 + r * 128 + byt) = vb;
    }
    __syncthreads();
    #pragma unroll
    for (int kc = 0; kc < 8; ++kc) {
      const char* ab = At + kc * 8192 + bsub * 2048;
      bf16x8 aL = *(const bf16x8*)(ab + lo);
      bf16x8 aH = *(const bf16x8*)(ab + hi);
      const char* bb0 = Bt + kc * 8192 + (epair * 2) * 2048;
      const char* bb1 = bb0 + 2048;
      c0 = __builtin_amdgcn_mfma_f32_16x16x32_bf16(aL, *(const bf16x8*)(bb0 + lo), c0, 0, 0, 0);
      c0 = __builtin_amdgcn_mfma_f32_16x16x32_bf16(aH, *(const bf16x8*)(bb0 + hi), c0, 0, 0, 0);
      c1 = __builtin_amdgcn_mfma_f32_16x16x32_bf16(aL, *(const bf16x8*)(bb1 + lo), c1, 0, 0, 0);
      c1 = __builtin_amdgcn_mfma_f32_16x16x32_bf16(aH, *(const bf16x8*)(bb1 + hi), c1, 0, 0, 0);
    }
    __syncthreads();
  }
  const int brow = b0 + bsub * 16 + (lane >> 4) * 4;
  const int ec0 = e0 + (epair * 2) * 16 + (lane & 15);
  const float bo0 = bout[ec0], bo1 = bout[ec0 + 16];
  #pragma unroll
  for (int r = 0; r < 4; ++r) {
    Sw[(size_t)(brow + r) * 512 + ec0] = c0[r] + bo0;
    Sw[(size_t)(brow + r) * 512 + ec0 + 16] = c1[r] + bo1;
  }
}

// ================= K4: spectral phase (unchanged, verified) =================
#define K4_LDS 141312
__global__ __launch_bounds__(512, 2)
void k4_spec(const float* __restrict__ x, const char* __restrict__ Cws,
             const float* __restrict__ Sw, float* __restrict__ out) {
  extern __shared__ char smem[];
  char* xTc = smem;
  char* w2Tc = smem + 65536;
  char* Cc = smem + 131072;
  float* s_l = (float*)(smem + 139264);

  const int t = threadIdx.x;
  const int lane = t & 63;
  const int wave = t >> 6;
  const int b = blockIdx.x;
  const float* xb = x + (size_t)b * NP * DIM;

  const int lo_off = ((lane & 15) * 128) + ((((lane >> 4) * 16)) ^ ((lane & 7) << 4));
  const int hi_off = ((lane & 15) * 128) + ((((lane >> 4) * 16) + 64) ^ ((lane & 7) << 4));

  {
    const int d = t;
    #pragma unroll
    for (int c = 0; c < 8; ++c) {
      float v0 = xb[(c * 8 + 0) * DIM + d];
      float v1 = xb[(c * 8 + 1) * DIM + d];
      float v2 = xb[(c * 8 + 2) * DIM + d];
      float v3 = xb[(c * 8 + 3) * DIM + d];
      float v4 = xb[(c * 8 + 4) * DIM + d];
      float v5 = xb[(c * 8 + 5) * DIM + d];
      float v6 = xb[(c * 8 + 6) * DIM + d];
      float v7 = xb[(c * 8 + 7) * DIM + d];
      uint4 pk;
      pk.x = pk2(v0, v1);
      pk.y = pk2(v2, v3);
      pk.z = pk2(v4, v5);
      pk.w = pk2(v6, v7);
      *(uint4*)(xTc + d * 128 + ((c * 16) ^ ((d & 7) << 4))) = pk;
    }
    ((uint4*)Cc)[t] = ((const uint4*)Cws)[t];
    s_l[t] = Sw[(size_t)b * 512 + t];
  }
  __syncthreads();

  {
    bf16x8 af0[4], af1[4];
    #pragma unroll
    for (int mt = 0; mt < 4; ++mt) {
      af0[mt] = *(const bf16x8*)(Cc + mt * 16 * 128 + lo_off);
      af1[mt] = *(const bf16x8*)(Cc + mt * 16 * 128 + hi_off);
    }
    #pragma unroll
    for (int etl = 0; etl < 4; ++etl) {
      const int e0 = (wave * 4 + etl) * 16;
      bf16x8 b0 = *(const bf16x8*)(xTc + e0 * 128 + lo_off);
      bf16x8 b1 = *(const bf16x8*)(xTc + e0 * 128 + hi_off);
      #pragma unroll
      for (int mt = 0; mt < 4; ++mt) {
        f32x4 c = {0.f, 0.f, 0.f, 0.f};
        c = __builtin_amdgcn_mfma_f32_16x16x32_bf16(af0[mt], b0, c, 0, 0, 0);
        c = __builtin_amdgcn_mfma_f32_16x16x32_bf16(af1[mt], b1, c, 0, 0, 0);
        const int e = e0 + (lane & 15);
        const int mrow = mt * 16 + (lane >> 4) * 4;
        uint2 pk;
        pk.x = pk2(c[0], c[1]);
        pk.y = pk2(c[2], c[3]);
        *(uint2*)(w2Tc + e * 128 + ((mrow * 2) ^ ((e & 7) << 4))) = pk;
      }
    }
  }
  __syncthreads();

  float treg[32];
  #pragma unroll
  for (int et = 0; et < 32; ++et) treg[et] = 0.f;

  for (int pass = 0; pass < 4; ++pass) {
    const int d0 = pass * 128 + wave * 16;
    bf16x8 a0 = *(const bf16x8*)(xTc + d0 * 128 + lo_off);
    bf16x8 a1 = *(const bf16x8*)(xTc + d0 * 128 + hi_off);
    f32x4 acc[32];
    #pragma unroll
    for (int et = 0; et < 32; ++et) {
      bf16x8 b0 = *(const bf16x8*)(w2Tc + et * 2048 + lo_off);
      bf16x8 b1 = *(const bf16x8*)(w2Tc + et * 2048 + hi_off);
      f32x4 c = {0.f, 0.f, 0.f, 0.f};
      c = __builtin_amdgcn_mfma_f32_16x16x32_bf16(a0, b0, c, 0, 0, 0);
      c = __builtin_amdgcn_mfma_f32_16x16x32_bf16(a1, b1, c, 0, 0, 0);
      acc[et] = c;
    }
    float rs[4] = {0.f, 0.f, 0.f, 0.f};
    #pragma unroll
    for (int et = 0; et < 32; ++et) {
      #pragma unroll
      for (int r = 0; r < 4; ++r) {
        float ev = __expf(acc[et][r]);
        acc[et][r] = ev;
        rs[r] += ev;
      }
    }
    #pragma unroll
    for (int r = 0; r < 4; ++r) {
      rs[r] += __shfl_xor(rs[r], 1);
      rs[r] += __shfl_xor(rs[r], 2);
      rs[r] += __shfl_xor(rs[r], 4);
      rs[r] += __shfl_xor(rs[r], 8);
    }
    float coef[4];
    #pragma unroll
    for (int r = 0; r < 4; ++r)
      coef[r] = s_l[d0 + (lane >> 4) * 4 + r] / rs[r];
    #pragma unroll
    for (int et = 0; et < 32; ++et) {
      float tp = treg[et];
      tp = fmaf(coef[0], acc[et][0], tp);
      tp = fmaf(coef[1], acc[et][1], tp);
      tp = fmaf(coef[2], acc[et][2], tp);
      tp = fmaf(coef[3], acc[et][3], tp);
      treg[et] = tp;
    }
  }
  __syncthreads();

  #pragma unroll
  for (int et = 0; et < 32; ++et) {
    treg[et] += __shfl_xor(treg[et], 16);
    treg[et] += __shfl_xor(treg[et], 32);
  }
  float* wpart = (float*)xTc;  // [8][512]
  if (lane < 16) {
    #pragma unroll
    for (int et = 0; et < 32; ++et)
      wpart[wave * 512 + et * 16 + lane] = treg[et];
  }
  __syncthreads();

  float tf = 0.f;
  #pragma unroll
  for (int w = 0; w < 8; ++w) tf += wpart[w * 512 + t];

  float* ob = out + (size_t)b * NP * DIM + t;
  #pragma unroll 4
  for (int n = 0; n < NP; ++n) ob[n * DIM] = tf;
}

extern "C" void kernel_launch(void* const* d_in, const int* in_sizes, int n_in,
                              void* d_out, int out_size, void* d_ws, size_t ws_size,
                              hipStream_t stream) {
  (void)in_sizes; (void)n_in; (void)out_size; (void)ws_size;
  const float* x     = (const float*)d_in[0];
  const float* Wq    = (const float*)d_in[1];
  const float* Wkv   = (const float*)d_in[2];
  const float* Wout  = (const float*)d_in[3];
  const float* bout  = (const float*)d_in[4];
  const float* Wspec = (const float*)d_in[5];
  float* out = (float*)d_out;

  char* ws = (char*)d_ws;

  hipFuncSetAttribute(reinterpret_cast<const void*>(ku_u),
                      hipFuncAttributeMaxDynamicSharedMemorySize, GEMM_LDS);
  hipFuncSetAttribute(reinterpret_cast<const void*>(ks_s),
                      hipFuncAttributeMaxDynamicSharedMemorySize, GEMM_LDS);
  hipFuncSetAttribute(reinterpret_cast<const void*>(k4_spec),
                      hipFuncAttributeMaxDynamicSharedMemorySize, K4_LDS);

  kw_prep<<<dim3(1025), dim3(512), 0, stream>>>(Wq, Wkv, Wout, Wspec, ws);
  ku_u   <<<dim3(256),  dim3(512), GEMM_LDS, stream>>>(x, ws, ws + WS_U);
  k2_attn<<<dim3(256),  dim3(512), 0, stream>>>(x, ws + WS_U, ws + WS_Y);
  ks_s   <<<dim3(32),   dim3(512), GEMM_LDS, stream>>>(ws + WS_Y, ws, bout,
                                                       (float*)(ws + WS_S));
  k4_spec<<<dim3(256),  dim3(512), K4_LDS, stream>>>(x, ws, (const float*)(ws + WS_S), out);
}

// Round 7
// 141.435 us; speedup vs baseline: 2.9050x; 1.3999x over previous
//
#include <hip/hip_runtime.h>

#define NP 64
#define DIM 512
#define NH 8
#define SCALE 0.125f

typedef __attribute__((ext_vector_type(4))) float f32x4;
typedef __attribute__((ext_vector_type(8))) short bf16x8;

// ---------------- workspace layout (bytes), total ~12.6 MB ----------------
#define WS_C   0                 // bf16 C[64][64] swizzled (8 KB)
#define WS_MT  8192              // bf16 Mt[4096 n=(h,e)][512 k=d]   (4 MB)
#define WS_PT  4202496           // bf16 Pt[512 e][4096 K=(h,d)]    (4 MB)
#define WS_U   8396800           // bf16 U[256 b][4096 n=(h,e)]     (2 MB)
#define WS_Y   10493952          // bf16 Y[256 b][4096 K=(h,d)]     (2 MB)
#define WS_S   12591104          // f32  S[256 b][512 e]            (512 KB)

static __device__ __forceinline__ unsigned short f2bf(float f) {
  unsigned int u = __builtin_bit_cast(unsigned int, f);
  u += 0x7fffu + ((u >> 16) & 1u);
  return (unsigned short)(u >> 16);
}
static __device__ __forceinline__ float bf2f(unsigned short s) {
  return __builtin_bit_cast(float, ((unsigned int)s) << 16);
}
static __device__ __forceinline__ unsigned pk2(float a, float b) {
  return (unsigned)f2bf(a) | ((unsigned)f2bf(b) << 16);
}

// ================= KW: batch-independent precompute =================
__global__ __launch_bounds__(512)
void kw_prep(const float* __restrict__ Wq, const float* __restrict__ Wkv,
             const float* __restrict__ Wout, const float* __restrict__ Wspec,
             char* __restrict__ ws) {
  __shared__ float wa[64 * 65];
  __shared__ float wb[64 * 65];
  const int t = threadIdx.x;
  const int blk = blockIdx.x;
  const int sr = t >> 3, sc8 = (t & 7) * 8;

  if (blk == 1024) {
    #pragma unroll
    for (int cc = 0; cc < 8; ++cc) {
      wa[sr * 65 + sc8 + cc] = Wspec[sr * 192 + sc8 + cc];
      wb[sr * 65 + sc8 + cc] = Wspec[sr * 192 + 64 + sc8 + cc];
    }
    __syncthreads();
    const int m = sr, mm0 = sc8;
    float acc[8] = {0.f, 0.f, 0.f, 0.f, 0.f, 0.f, 0.f, 0.f};
    for (int n = 0; n < 64; ++n) {
      float qv = wa[m * 65 + n];
      #pragma unroll
      for (int j = 0; j < 8; ++j)
        acc[j] = fmaf(qv, wb[(mm0 + j) * 65 + n], acc[j]);
    }
    uint4 pk;
    pk.x = pk2(acc[0] * SCALE, acc[1] * SCALE);
    pk.y = pk2(acc[2] * SCALE, acc[3] * SCALE);
    pk.z = pk2(acc[4] * SCALE, acc[5] * SCALE);
    pk.w = pk2(acc[6] * SCALE, acc[7] * SCALE);
    *(uint4*)(ws + WS_C + m * 128 + ((mm0 * 2) ^ ((m & 7) << 4))) = pk;
    return;
  }

  const bool isP = blk >= 512;
  const int id = blk & 511;
  const int h = id >> 6, et = (id >> 3) & 7, dt = id & 7;

  const float* sa = isP ? (Wkv + (size_t)(dt * 64 + sr) * 1024 + 512 + h * 64)
                        : (Wq + (size_t)(dt * 64 + sr) * 512 + h * 64);
  const float* sb = isP ? (Wout + (size_t)(h * 64 + sr) * 512 + et * 64)
                        : (Wkv + (size_t)(et * 64 + sr) * 1024 + h * 64);
  {
    float4 a0 = *(const float4*)(sa + sc8), a1 = *(const float4*)(sa + sc8 + 4);
    float* d = wa + sr * 65 + sc8;
    d[0] = a0.x; d[1] = a0.y; d[2] = a0.z; d[3] = a0.w;
    d[4] = a1.x; d[5] = a1.y; d[6] = a1.z; d[7] = a1.w;
    float4 b0 = *(const float4*)(sb + sc8), b1 = *(const float4*)(sb + sc8 + 4);
    float* e = wb + sr * 65 + sc8;
    e[0] = b0.x; e[1] = b0.y; e[2] = b0.z; e[3] = b0.w;
    e[4] = b1.x; e[5] = b1.y; e[6] = b1.z; e[7] = b1.w;
  }
  __syncthreads();

  const int er = sr, dc8 = sc8;
  float acc[8] = {0.f, 0.f, 0.f, 0.f, 0.f, 0.f, 0.f, 0.f};
  if (!isP) {
    for (int j = 0; j < 64; ++j) {
      float bv = wb[er * 65 + j];
      #pragma unroll
      for (int dd = 0; dd < 8; ++dd)
        acc[dd] = fmaf(bv, wa[(dc8 + dd) * 65 + j], acc[dd]);
    }
  } else {
    for (int j = 0; j < 64; ++j) {
      float bv = wb[j * 65 + er];
      #pragma unroll
      for (int dd = 0; dd < 8; ++dd)
        acc[dd] = fmaf(bv, wa[(dc8 + dd) * 65 + j], acc[dd]);
    }
  }
  uint4 pk;
  pk.x = pk2(acc[0], acc[1]);
  pk.y = pk2(acc[2], acc[3]);
  pk.z = pk2(acc[4], acc[5]);
  pk.w = pk2(acc[6], acc[7]);
  if (!isP)
    *(uint4*)(ws + WS_MT + ((size_t)(h * 512 + et * 64 + er) * 512 + dt * 64 + dc8) * 2) = pk;
  else
    *(uint4*)(ws + WS_PT + ((size_t)(et * 64 + er) * 4096 + h * 512 + dt * 64 + dc8) * 2) = pk;
}

// ================= KU: U[256][4096] = XC[256][512] @ Mt^T (bf16 MFMA) =================
#define GEMM_LDS 131072
__global__ __launch_bounds__(512, 2)
void ku_u(const float* __restrict__ x, const char* __restrict__ ws,
          char* __restrict__ ws_u) {
  extern __shared__ char sm[];
  char* At = sm;
  char* Bt = sm + 65536;
  const int t = threadIdx.x, lane = t & 63, wave = t >> 6;
  const int bt = blockIdx.x >> 6, nt = blockIdx.x & 63;
  const int b0 = bt * 64, n0 = nt * 64;
  const char* Mt = ws + WS_MT;

  #pragma unroll
  for (int i = 0; i < 8; ++i) {
    const int r = wave * 8 + i;
    const float4* xr = (const float4*)(x + ((size_t)(b0 + r) * 64 + 32) * 512);
    float4 a = xr[lane], c = xr[64 + lane];
    uint2 pa = {pk2(a.x, a.y), pk2(a.z, a.w)};
    uint2 pc = {pk2(c.x, c.y), pk2(c.z, c.w)};
    const int swz = (r & 7) << 4;
    const int byt = (8 * (lane & 15)) ^ swz;
    *(uint2*)(At + (lane >> 4) * 8192 + r * 128 + byt) = pa;
    *(uint2*)(At + (4 + (lane >> 4)) * 8192 + r * 128 + byt) = pc;
  }
  #pragma unroll
  for (int i = 0; i < 8; ++i) {
    const int r = wave * 8 + i;
    uint4 v = ((const uint4*)(Mt + (size_t)(n0 + r) * 1024))[lane];
    *(uint4*)(Bt + (lane >> 3) * 8192 + r * 128 + ((16 * (lane & 7)) ^ ((r & 7) << 4))) = v;
  }
  __syncthreads();

  const int lo = ((lane & 15) * 128) + (((lane >> 4) * 16) ^ ((lane & 7) << 4));
  const int hi = ((lane & 15) * 128) + ((((lane >> 4) * 16) + 64) ^ ((lane & 7) << 4));
  const int bsub = wave & 3, npair = wave >> 2;

  f32x4 c0 = {0.f, 0.f, 0.f, 0.f}, c1 = {0.f, 0.f, 0.f, 0.f};
  #pragma unroll
  for (int kc = 0; kc < 8; ++kc) {
    const char* ab = At + kc * 8192 + bsub * 2048;
    bf16x8 aL = *(const bf16x8*)(ab + lo);
    bf16x8 aH = *(const bf16x8*)(ab + hi);
    const char* bb0 = Bt + kc * 8192 + (npair * 2) * 2048;
    const char* bb1 = bb0 + 2048;
    c0 = __builtin_amdgcn_mfma_f32_16x16x32_bf16(aL, *(const bf16x8*)(bb0 + lo), c0, 0, 0, 0);
    c0 = __builtin_amdgcn_mfma_f32_16x16x32_bf16(aH, *(const bf16x8*)(bb0 + hi), c0, 0, 0, 0);
    c1 = __builtin_amdgcn_mfma_f32_16x16x32_bf16(aL, *(const bf16x8*)(bb1 + lo), c1, 0, 0, 0);
    c1 = __builtin_amdgcn_mfma_f32_16x16x32_bf16(aH, *(const bf16x8*)(bb1 + hi), c1, 0, 0, 0);
  }
  unsigned short* U = (unsigned short*)ws_u;
  const int brow = b0 + bsub * 16 + (lane >> 4) * 4;
  const int nc0 = n0 + (npair * 2) * 16 + (lane & 15);
  #pragma unroll
  for (int r = 0; r < 4; ++r) {
    U[(size_t)(brow + r) * 4096 + nc0] = f2bf(c0[r]);
    U[(size_t)(brow + r) * 4096 + nc0 + 16] = f2bf(c1[r]);
  }
}

// ================= K2: batch-local spatial attention =================
__global__ __launch_bounds__(512)
void k2_attn(const float* __restrict__ x, const char* __restrict__ ws_u,
             char* __restrict__ ws_y) {
  __shared__ float ul[8 * 512];
  __shared__ float scoreL[8 * 64];
  __shared__ float pT[64 * 8];
  const int t = threadIdx.x;
  const int lane = t & 63;
  const int wave = t >> 6;
  const int b = blockIdx.x;
  const float* xb = x + (size_t)b * NP * DIM;

  {
    uint4 v = ((const uint4*)(ws_u + (size_t)b * 8192))[t];
    const unsigned short* pv = (const unsigned short*)&v;
    float* d = ul + t * 8;
    #pragma unroll
    for (int g = 0; g < 8; ++g) d[g] = bf2f(pv[g]);
  }
  __syncthreads();

  {
    float4 uf0[8], uf1[8];
    #pragma unroll
    for (int h = 0; h < 8; ++h) {
      uf0[h] = *(const float4*)(ul + h * 512 + 4 * lane);
      uf1[h] = *(const float4*)(ul + h * 512 + 256 + 4 * lane);
    }
    #pragma unroll 2
    for (int i = 0; i < 8; ++i) {
      const int m = wave * 8 + i;
      const float4* xr = (const float4*)(xb + (size_t)m * DIM);
      float4 xv0 = xr[lane];
      float4 xv1 = xr[64 + lane];
      #pragma unroll
      for (int h = 0; h < 8; ++h) {
        float p = xv0.x * uf0[h].x + xv0.y * uf0[h].y + xv0.z * uf0[h].z + xv0.w * uf0[h].w
                + xv1.x * uf1[h].x + xv1.y * uf1[h].y + xv1.z * uf1[h].z + xv1.w * uf1[h].w;
        p += __shfl_xor(p, 1);
        p += __shfl_xor(p, 2);
        p += __shfl_xor(p, 4);
        p += __shfl_xor(p, 8);
        p += __shfl_xor(p, 16);
        p += __shfl_xor(p, 32);
        if (lane == 0) scoreL[h * 64 + m] = p;
      }
    }
  }
  __syncthreads();

  {
    float sc = scoreL[wave * 64 + lane] * SCALE;
    float mx = sc;
    #pragma unroll
    for (int off = 32; off > 0; off >>= 1)
      mx = fmaxf(mx, __shfl_xor(mx, off));
    float ev = __expf(sc - mx);
    float sm = ev;
    #pragma unroll
    for (int off = 32; off > 0; off >>= 1)
      sm += __shfl_xor(sm, off);
    pT[lane * NH + wave] = ev / sm;
  }
  __syncthreads();

  {
    float acc[NH];
    #pragma unroll
    for (int h = 0; h < NH; ++h) acc[h] = 0.f;
    #pragma unroll 2
    for (int m = 0; m < NP; ++m) {
      float xv = xb[(size_t)m * DIM + t];
      const float4* pp = (const float4*)(pT + m * NH);
      float4 p0 = pp[0], p1 = pp[1];
      acc[0] = fmaf(p0.x, xv, acc[0]);
      acc[1] = fmaf(p0.y, xv, acc[1]);
      acc[2] = fmaf(p0.z, xv, acc[2]);
      acc[3] = fmaf(p0.w, xv, acc[3]);
      acc[4] = fmaf(p1.x, xv, acc[4]);
      acc[5] = fmaf(p1.y, xv, acc[5]);
      acc[6] = fmaf(p1.z, xv, acc[6]);
      acc[7] = fmaf(p1.w, xv, acc[7]);
    }
    unsigned short* Y = (unsigned short*)ws_y;
    #pragma unroll
    for (int h = 0; h < NH; ++h)
      Y[(size_t)b * 4096 + h * 512 + t] = f2bf(acc[h]);
  }
}

// ================= KS: S[256][512] = Ycat[256][4096] @ Pt^T + bout (bf16 MFMA) =================
__global__ __launch_bounds__(512, 2)
void ks_s(const char* __restrict__ ws_y, const char* __restrict__ ws,
          const float* __restrict__ bout, float* __restrict__ Sw) {
  extern __shared__ char sm[];
  char* At = sm;
  char* Bt = sm + 65536;
  const int t = threadIdx.x, lane = t & 63, wave = t >> 6;
  const int bt = blockIdx.x >> 3, et = blockIdx.x & 7;
  const int b0 = bt * 64, e0 = et * 64;
  const char* Pt = ws + WS_PT;

  const int lo = ((lane & 15) * 128) + (((lane >> 4) * 16) ^ ((lane & 7) << 4));
  const int hi = ((lane & 15) * 128) + ((((lane >> 4) * 16) + 64) ^ ((lane & 7) << 4));
  const int bsub = wave & 3, epair = wave >> 2;

  f32x4 c0 = {0.f, 0.f, 0.f, 0.f}, c1 = {0.f, 0.f, 0.f, 0.f};
  for (int it = 0; it < 8; ++it) {
    const size_t kb2 = (size_t)it * 1024;
    #pragma unroll
    for (int i = 0; i < 8; ++i) {
      const int r = wave * 8 + i;
      const int byt = (16 * (lane & 7)) ^ ((r & 7) << 4);
      uint4 va = ((const uint4*)(ws_y + (size_t)(b0 + r) * 8192 + kb2))[lane];
      *(uint4*)(At + (lane >> 3) * 8192 + r * 128 + byt) = va;
      uint4 vb = ((const uint4*)(Pt + (size_t)(e0 + r) * 8192 + kb2))[lane];
      *(uint4*)(Bt + (lane >> 3) * 8192 + r * 128 + byt) = vb;
    }
    __syncthreads();
    #pragma unroll
    for (int kc = 0; kc < 8; ++kc) {
      const char* ab = At + kc * 8192 + bsub * 2048;
      bf16x8 aL = *(const bf16x8*)(ab + lo);
      bf16x8 aH = *(const bf16x8*)(ab + hi);
      const char* bb0 = Bt + kc * 8192 + (epair * 2) * 2048;
      const char* bb1 = bb0 + 2048;
      c0 = __builtin_amdgcn_mfma_f32_16x16x32_bf16(aL, *(const bf16x8*)(bb0 + lo), c0, 0, 0, 0);
      c0 = __builtin_amdgcn_mfma_f32_16x16x32_bf16(aH, *(const bf16x8*)(bb0 + hi), c0, 0, 0, 0);
      c1 = __builtin_amdgcn_mfma_f32_16x16x32_bf16(aL, *(const bf16x8*)(bb1 + lo), c1, 0, 0, 0);
      c1 = __builtin_amdgcn_mfma_f32_16x16x32_bf16(aH, *(const bf16x8*)(bb1 + hi), c1, 0, 0, 0);
    }
    __syncthreads();
  }
  const int brow = b0 + bsub * 16 + (lane >> 4) * 4;
  const int ec0 = e0 + (epair * 2) * 16 + (lane & 15);
  const float bo0 = bout[ec0], bo1 = bout[ec0 + 16];
  #pragma unroll
  for (int r = 0; r < 4; ++r) {
    Sw[(size_t)(brow + r) * 512 + ec0] = c0[r] + bo0;
    Sw[(size_t)(brow + r) * 512 + ec0 + 16] = c1[r] + bo1;
  }
}

// ================= K4: spectral phase — two-pass chunked softmax (no acc[32] spill) =================
#define K4_LDS 141312
__global__ __launch_bounds__(512, 2)
void k4_spec(const float* __restrict__ x, const char* __restrict__ Cws,
             const float* __restrict__ Sw, float* __restrict__ out) {
  extern __shared__ char smem[];
  char* xTc = smem;
  char* w2Tc = smem + 65536;
  char* Cc = smem + 131072;
  float* s_l = (float*)(smem + 139264);

  const int t = threadIdx.x;
  const int lane = t & 63;
  const int wave = t >> 6;
  const int b = blockIdx.x;
  const float* xb = x + (size_t)b * NP * DIM;

  const int lo_off = ((lane & 15) * 128) + ((((lane >> 4) * 16)) ^ ((lane & 7) << 4));
  const int hi_off = ((lane & 15) * 128) + ((((lane >> 4) * 16) + 64) ^ ((lane & 7) << 4));

  {
    const int d = t;
    #pragma unroll
    for (int c = 0; c < 8; ++c) {
      float v0 = xb[(c * 8 + 0) * DIM + d];
      float v1 = xb[(c * 8 + 1) * DIM + d];
      float v2 = xb[(c * 8 + 2) * DIM + d];
      float v3 = xb[(c * 8 + 3) * DIM + d];
      float v4 = xb[(c * 8 + 4) * DIM + d];
      float v5 = xb[(c * 8 + 5) * DIM + d];
      float v6 = xb[(c * 8 + 6) * DIM + d];
      float v7 = xb[(c * 8 + 7) * DIM + d];
      uint4 pk;
      pk.x = pk2(v0, v1);
      pk.y = pk2(v2, v3);
      pk.z = pk2(v4, v5);
      pk.w = pk2(v6, v7);
      *(uint4*)(xTc + d * 128 + ((c * 16) ^ ((d & 7) << 4))) = pk;
    }
    ((uint4*)Cc)[t] = ((const uint4*)Cws)[t];
    s_l[t] = Sw[(size_t)b * 512 + t];
  }
  __syncthreads();

  // W2-MFMA: W2[m][e] = sum_mm C[m][mm] * x[mm][e]; write w2T[e][m] bf16 swizzled
  {
    bf16x8 af0[4], af1[4];
    #pragma unroll
    for (int mt = 0; mt < 4; ++mt) {
      af0[mt] = *(const bf16x8*)(Cc + mt * 16 * 128 + lo_off);
      af1[mt] = *(const bf16x8*)(Cc + mt * 16 * 128 + hi_off);
    }
    #pragma unroll
    for (int etl = 0; etl < 4; ++etl) {
      const int e0 = (wave * 4 + etl) * 16;
      bf16x8 b0 = *(const bf16x8*)(xTc + e0 * 128 + lo_off);
      bf16x8 b1 = *(const bf16x8*)(xTc + e0 * 128 + hi_off);
      #pragma unroll
      for (int mt = 0; mt < 4; ++mt) {
        f32x4 c = {0.f, 0.f, 0.f, 0.f};
        c = __builtin_amdgcn_mfma_f32_16x16x32_bf16(af0[mt], b0, c, 0, 0, 0);
        c = __builtin_amdgcn_mfma_f32_16x16x32_bf16(af1[mt], b1, c, 0, 0, 0);
        const int e = e0 + (lane & 15);
        const int mrow = mt * 16 + (lane >> 4) * 4;
        uint2 pk;
        pk.x = pk2(c[0], c[1]);
        pk.y = pk2(c[2], c[3]);
        *(uint2*)(w2Tc + e * 128 + ((mrow * 2) ^ ((e & 7) << 4))) = pk;
      }
    }
  }
  __syncthreads();

  // Phase C: two passes per d-block — (A) row sums via MFMA+exp (acc dies per et),
  // (B) recompute identical MFMAs, weight by coef. No acc[32] -> no scratch spill.
  float treg[32];
  #pragma unroll
  for (int et = 0; et < 32; ++et) treg[et] = 0.f;

  for (int pass = 0; pass < 4; ++pass) {
    const int d0 = pass * 128 + wave * 16;
    bf16x8 a0 = *(const bf16x8*)(xTc + d0 * 128 + lo_off);
    bf16x8 a1 = *(const bf16x8*)(xTc + d0 * 128 + hi_off);

    float rs[4] = {0.f, 0.f, 0.f, 0.f};
    #pragma unroll 4
    for (int et = 0; et < 32; ++et) {
      bf16x8 b0 = *(const bf16x8*)(w2Tc + et * 2048 + lo_off);
      bf16x8 b1 = *(const bf16x8*)(w2Tc + et * 2048 + hi_off);
      f32x4 c = {0.f, 0.f, 0.f, 0.f};
      c = __builtin_amdgcn_mfma_f32_16x16x32_bf16(a0, b0, c, 0, 0, 0);
      c = __builtin_amdgcn_mfma_f32_16x16x32_bf16(a1, b1, c, 0, 0, 0);
      rs[0] += __expf(c[0]);
      rs[1] += __expf(c[1]);
      rs[2] += __expf(c[2]);
      rs[3] += __expf(c[3]);
    }
    #pragma unroll
    for (int r = 0; r < 4; ++r) {
      rs[r] += __shfl_xor(rs[r], 1);
      rs[r] += __shfl_xor(rs[r], 2);
      rs[r] += __shfl_xor(rs[r], 4);
      rs[r] += __shfl_xor(rs[r], 8);
    }
    float coef[4];
    #pragma unroll
    for (int r = 0; r < 4; ++r)
      coef[r] = s_l[d0 + (lane >> 4) * 4 + r] / rs[r];

    #pragma unroll 4
    for (int et = 0; et < 32; ++et) {
      bf16x8 b0 = *(const bf16x8*)(w2Tc + et * 2048 + lo_off);
      bf16x8 b1 = *(const bf16x8*)(w2Tc + et * 2048 + hi_off);
      f32x4 c = {0.f, 0.f, 0.f, 0.f};
      c = __builtin_amdgcn_mfma_f32_16x16x32_bf16(a0, b0, c, 0, 0, 0);
      c = __builtin_amdgcn_mfma_f32_16x16x32_bf16(a1, b1, c, 0, 0, 0);
      float tp = treg[et];
      tp = fmaf(coef[0], __expf(c[0]), tp);
      tp = fmaf(coef[1], __expf(c[1]), tp);
      tp = fmaf(coef[2], __expf(c[2]), tp);
      tp = fmaf(coef[3], __expf(c[3]), tp);
      treg[et] = tp;
    }
  }
  __syncthreads();

  #pragma unroll
  for (int et = 0; et < 32; ++et) {
    treg[et] += __shfl_xor(treg[et], 16);
    treg[et] += __shfl_xor(treg[et], 32);
  }
  float* wpart = (float*)xTc;  // [8][512]
  if (lane < 16) {
    #pragma unroll
    for (int et = 0; et < 32; ++et)
      wpart[wave * 512 + et * 16 + lane] = treg[et];
  }
  __syncthreads();

  float tf = 0.f;
  #pragma unroll
  for (int w = 0; w < 8; ++w) tf += wpart[w * 512 + t];

  float* ob = out + (size_t)b * NP * DIM + t;
  #pragma unroll 4
  for (int n = 0; n < NP; ++n) ob[n * DIM] = tf;
}

extern "C" void kernel_launch(void* const* d_in, const int* in_sizes, int n_in,
                              void* d_out, int out_size, void* d_ws, size_t ws_size,
                              hipStream_t stream) {
  (void)in_sizes; (void)n_in; (void)out_size; (void)ws_size;
  const float* x     = (const float*)d_in[0];
  const float* Wq    = (const float*)d_in[1];
  const float* Wkv   = (const float*)d_in[2];
  const float* Wout  = (const float*)d_in[3];
  const float* bout  = (const float*)d_in[4];
  const float* Wspec = (const float*)d_in[5];
  float* out = (float*)d_out;

  char* ws = (char*)d_ws;

  hipFuncSetAttribute(reinterpret_cast<const void*>(ku_u),
                      hipFuncAttributeMaxDynamicSharedMemorySize, GEMM_LDS);
  hipFuncSetAttribute(reinterpret_cast<const void*>(ks_s),
                      hipFuncAttributeMaxDynamicSharedMemorySize, GEMM_LDS);
  hipFuncSetAttribute(reinterpret_cast<const void*>(k4_spec),
                      hipFuncAttributeMaxDynamicSharedMemorySize, K4_LDS);

  kw_prep<<<dim3(1025), dim3(512), 0, stream>>>(Wq, Wkv, Wout, Wspec, ws);
  ku_u   <<<dim3(256),  dim3(512), GEMM_LDS, stream>>>(x, ws, ws + WS_U);
  k2_attn<<<dim3(256),  dim3(512), 0, stream>>>(x, ws + WS_U, ws + WS_Y);
  ks_s   <<<dim3(32),   dim3(512), GEMM_LDS, stream>>>(ws + WS_Y, ws, bout,
                                                       (float*)(ws + WS_S));
  k4_spec<<<dim3(256),  dim3(512), K4_LDS, stream>>>(x, ws, (const float*)(ws + WS_S), out);
}

// Round 8
// 116.431 us; speedup vs baseline: 3.5289x; 1.2148x over previous
//
#include <hip/hip_runtime.h>

#define NP 64
#define DIM 512
#define NH 8
#define SCALE 0.125f

typedef __attribute__((ext_vector_type(4))) float f32x4;
typedef __attribute__((ext_vector_type(8))) short bf16x8;

// ---------------- workspace layout (bytes), high-water ~12.6 MB ----------------
// WS_MT region is reused: Mt (kw->ku) then S-partials (ks->k4).
#define WS_C   0                 // bf16 C[64][64] swizzled (8 KB)
#define WS_MT  8192              // bf16 Mt[4096][512] (4 MB)  -> then f32 Spart[8][256][512] (4 MB)
#define WS_PT  4202496           // bf16 Pt[512 e][4096 K=(h,d)]    (4 MB)
#define WS_U   8396800           // bf16 U[256 b][4096 n=(h,e)]     (2 MB)
#define WS_Y   10493952          // bf16 Y[256 b][4096 K=(h,d)]     (2 MB)

static __device__ __forceinline__ unsigned short f2bf(float f) {
  unsigned int u = __builtin_bit_cast(unsigned int, f);
  u += 0x7fffu + ((u >> 16) & 1u);
  return (unsigned short)(u >> 16);
}
static __device__ __forceinline__ float bf2f(unsigned short s) {
  return __builtin_bit_cast(float, ((unsigned int)s) << 16);
}
static __device__ __forceinline__ unsigned pk2(float a, float b) {
  return (unsigned)f2bf(a) | ((unsigned)f2bf(b) << 16);
}

// ================= KW: batch-independent precompute =================
__global__ __launch_bounds__(512)
void kw_prep(const float* __restrict__ Wq, const float* __restrict__ Wkv,
             const float* __restrict__ Wout, const float* __restrict__ Wspec,
             char* __restrict__ ws) {
  __shared__ float wa[64 * 65];
  __shared__ float wb[64 * 65];
  const int t = threadIdx.x;
  const int blk = blockIdx.x;
  const int sr = t >> 3, sc8 = (t & 7) * 8;

  if (blk == 1024) {
    #pragma unroll
    for (int cc = 0; cc < 8; ++cc) {
      wa[sr * 65 + sc8 + cc] = Wspec[sr * 192 + sc8 + cc];
      wb[sr * 65 + sc8 + cc] = Wspec[sr * 192 + 64 + sc8 + cc];
    }
    __syncthreads();
    const int m = sr, mm0 = sc8;
    float acc[8] = {0.f, 0.f, 0.f, 0.f, 0.f, 0.f, 0.f, 0.f};
    for (int n = 0; n < 64; ++n) {
      float qv = wa[m * 65 + n];
      #pragma unroll
      for (int j = 0; j < 8; ++j)
        acc[j] = fmaf(qv, wb[(mm0 + j) * 65 + n], acc[j]);
    }
    uint4 pk;
    pk.x = pk2(acc[0] * SCALE, acc[1] * SCALE);
    pk.y = pk2(acc[2] * SCALE, acc[3] * SCALE);
    pk.z = pk2(acc[4] * SCALE, acc[5] * SCALE);
    pk.w = pk2(acc[6] * SCALE, acc[7] * SCALE);
    *(uint4*)(ws + WS_C + m * 128 + ((mm0 * 2) ^ ((m & 7) << 4))) = pk;
    return;
  }

  const bool isP = blk >= 512;
  const int id = blk & 511;
  const int h = id >> 6, et = (id >> 3) & 7, dt = id & 7;

  const float* sa = isP ? (Wkv + (size_t)(dt * 64 + sr) * 1024 + 512 + h * 64)
                        : (Wq + (size_t)(dt * 64 + sr) * 512 + h * 64);
  const float* sb = isP ? (Wout + (size_t)(h * 64 + sr) * 512 + et * 64)
                        : (Wkv + (size_t)(et * 64 + sr) * 1024 + h * 64);
  {
    float4 a0 = *(const float4*)(sa + sc8), a1 = *(const float4*)(sa + sc8 + 4);
    float* d = wa + sr * 65 + sc8;
    d[0] = a0.x; d[1] = a0.y; d[2] = a0.z; d[3] = a0.w;
    d[4] = a1.x; d[5] = a1.y; d[6] = a1.z; d[7] = a1.w;
    float4 b0 = *(const float4*)(sb + sc8), b1 = *(const float4*)(sb + sc8 + 4);
    float* e = wb + sr * 65 + sc8;
    e[0] = b0.x; e[1] = b0.y; e[2] = b0.z; e[3] = b0.w;
    e[4] = b1.x; e[5] = b1.y; e[6] = b1.z; e[7] = b1.w;
  }
  __syncthreads();

  const int er = sr, dc8 = sc8;
  float acc[8] = {0.f, 0.f, 0.f, 0.f, 0.f, 0.f, 0.f, 0.f};
  if (!isP) {
    for (int j = 0; j < 64; ++j) {
      float bv = wb[er * 65 + j];
      #pragma unroll
      for (int dd = 0; dd < 8; ++dd)
        acc[dd] = fmaf(bv, wa[(dc8 + dd) * 65 + j], acc[dd]);
    }
  } else {
    for (int j = 0; j < 64; ++j) {
      float bv = wb[j * 65 + er];
      #pragma unroll
      for (int dd = 0; dd < 8; ++dd)
        acc[dd] = fmaf(bv, wa[(dc8 + dd) * 65 + j], acc[dd]);
    }
  }
  uint4 pk;
  pk.x = pk2(acc[0], acc[1]);
  pk.y = pk2(acc[2], acc[3]);
  pk.z = pk2(acc[4], acc[5]);
  pk.w = pk2(acc[6], acc[7]);
  if (!isP)
    *(uint4*)(ws + WS_MT + ((size_t)(h * 512 + et * 64 + er) * 512 + dt * 64 + dc8) * 2) = pk;
  else
    *(uint4*)(ws + WS_PT + ((size_t)(et * 64 + er) * 4096 + h * 512 + dt * 64 + dc8) * 2) = pk;
}

// ================= KU: U[256][4096] = XC[256][512] @ Mt^T (bf16 MFMA) =================
#define GEMM_LDS 131072
__global__ __launch_bounds__(512, 2)
void ku_u(const float* __restrict__ x, const char* __restrict__ ws,
          char* __restrict__ ws_u) {
  extern __shared__ char sm[];
  char* At = sm;
  char* Bt = sm + 65536;
  const int t = threadIdx.x, lane = t & 63, wave = t >> 6;
  const int bt = blockIdx.x >> 6, nt = blockIdx.x & 63;
  const int b0 = bt * 64, n0 = nt * 64;
  const char* Mt = ws + WS_MT;

  #pragma unroll
  for (int i = 0; i < 8; ++i) {
    const int r = wave * 8 + i;
    const float4* xr = (const float4*)(x + ((size_t)(b0 + r) * 64 + 32) * 512);
    float4 a = xr[lane], c = xr[64 + lane];
    uint2 pa = {pk2(a.x, a.y), pk2(a.z, a.w)};
    uint2 pc = {pk2(c.x, c.y), pk2(c.z, c.w)};
    const int swz = (r & 7) << 4;
    const int byt = (8 * (lane & 15)) ^ swz;
    *(uint2*)(At + (lane >> 4) * 8192 + r * 128 + byt) = pa;
    *(uint2*)(At + (4 + (lane >> 4)) * 8192 + r * 128 + byt) = pc;
  }
  #pragma unroll
  for (int i = 0; i < 8; ++i) {
    const int r = wave * 8 + i;
    uint4 v = ((const uint4*)(Mt + (size_t)(n0 + r) * 1024))[lane];
    *(uint4*)(Bt + (lane >> 3) * 8192 + r * 128 + ((16 * (lane & 7)) ^ ((r & 7) << 4))) = v;
  }
  __syncthreads();

  const int lo = ((lane & 15) * 128) + (((lane >> 4) * 16) ^ ((lane & 7) << 4));
  const int hi = ((lane & 15) * 128) + ((((lane >> 4) * 16) + 64) ^ ((lane & 7) << 4));
  const int bsub = wave & 3, npair = wave >> 2;

  f32x4 c0 = {0.f, 0.f, 0.f, 0.f}, c1 = {0.f, 0.f, 0.f, 0.f};
  #pragma unroll
  for (int kc = 0; kc < 8; ++kc) {
    const char* ab = At + kc * 8192 + bsub * 2048;
    bf16x8 aL = *(const bf16x8*)(ab + lo);
    bf16x8 aH = *(const bf16x8*)(ab + hi);
    const char* bb0 = Bt + kc * 8192 + (npair * 2) * 2048;
    const char* bb1 = bb0 + 2048;
    c0 = __builtin_amdgcn_mfma_f32_16x16x32_bf16(aL, *(const bf16x8*)(bb0 + lo), c0, 0, 0, 0);
    c0 = __builtin_amdgcn_mfma_f32_16x16x32_bf16(aH, *(const bf16x8*)(bb0 + hi), c0, 0, 0, 0);
    c1 = __builtin_amdgcn_mfma_f32_16x16x32_bf16(aL, *(const bf16x8*)(bb1 + lo), c1, 0, 0, 0);
    c1 = __builtin_amdgcn_mfma_f32_16x16x32_bf16(aH, *(const bf16x8*)(bb1 + hi), c1, 0, 0, 0);
  }
  unsigned short* U = (unsigned short*)ws_u;
  const int brow = b0 + bsub * 16 + (lane >> 4) * 4;
  const int nc0 = n0 + (npair * 2) * 16 + (lane & 15);
  #pragma unroll
  for (int r = 0; r < 4; ++r) {
    U[(size_t)(brow + r) * 4096 + nc0] = f2bf(c0[r]);
    U[(size_t)(brow + r) * 4096 + nc0 + 16] = f2bf(c1[r]);
  }
}

// ================= K2: batch-local spatial attention =================
__global__ __launch_bounds__(512)
void k2_attn(const float* __restrict__ x, const char* __restrict__ ws_u,
             char* __restrict__ ws_y) {
  __shared__ float ul[8 * 512];
  __shared__ float scoreL[8 * 64];
  __shared__ float pT[64 * 8];
  const int t = threadIdx.x;
  const int lane = t & 63;
  const int wave = t >> 6;
  const int b = blockIdx.x;
  const float* xb = x + (size_t)b * NP * DIM;

  {
    uint4 v = ((const uint4*)(ws_u + (size_t)b * 8192))[t];
    const unsigned short* pv = (const unsigned short*)&v;
    float* d = ul + t * 8;
    #pragma unroll
    for (int g = 0; g < 8; ++g) d[g] = bf2f(pv[g]);
  }
  __syncthreads();

  {
    float4 uf0[8], uf1[8];
    #pragma unroll
    for (int h = 0; h < 8; ++h) {
      uf0[h] = *(const float4*)(ul + h * 512 + 4 * lane);
      uf1[h] = *(const float4*)(ul + h * 512 + 256 + 4 * lane);
    }
    #pragma unroll 2
    for (int i = 0; i < 8; ++i) {
      const int m = wave * 8 + i;
      const float4* xr = (const float4*)(xb + (size_t)m * DIM);
      float4 xv0 = xr[lane];
      float4 xv1 = xr[64 + lane];
      #pragma unroll
      for (int h = 0; h < 8; ++h) {
        float p = xv0.x * uf0[h].x + xv0.y * uf0[h].y + xv0.z * uf0[h].z + xv0.w * uf0[h].w
                + xv1.x * uf1[h].x + xv1.y * uf1[h].y + xv1.z * uf1[h].z + xv1.w * uf1[h].w;
        p += __shfl_xor(p, 1);
        p += __shfl_xor(p, 2);
        p += __shfl_xor(p, 4);
        p += __shfl_xor(p, 8);
        p += __shfl_xor(p, 16);
        p += __shfl_xor(p, 32);
        if (lane == 0) scoreL[h * 64 + m] = p;
      }
    }
  }
  __syncthreads();

  {
    float sc = scoreL[wave * 64 + lane] * SCALE;
    float mx = sc;
    #pragma unroll
    for (int off = 32; off > 0; off >>= 1)
      mx = fmaxf(mx, __shfl_xor(mx, off));
    float ev = __expf(sc - mx);
    float sm = ev;
    #pragma unroll
    for (int off = 32; off > 0; off >>= 1)
      sm += __shfl_xor(sm, off);
    pT[lane * NH + wave] = ev / sm;
  }
  __syncthreads();

  {
    float acc[NH];
    #pragma unroll
    for (int h = 0; h < NH; ++h) acc[h] = 0.f;
    #pragma unroll 2
    for (int m = 0; m < NP; ++m) {
      float xv = xb[(size_t)m * DIM + t];
      const float4* pp = (const float4*)(pT + m * NH);
      float4 p0 = pp[0], p1 = pp[1];
      acc[0] = fmaf(p0.x, xv, acc[0]);
      acc[1] = fmaf(p0.y, xv, acc[1]);
      acc[2] = fmaf(p0.z, xv, acc[2]);
      acc[3] = fmaf(p0.w, xv, acc[3]);
      acc[4] = fmaf(p1.x, xv, acc[4]);
      acc[5] = fmaf(p1.y, xv, acc[5]);
      acc[6] = fmaf(p1.z, xv, acc[6]);
      acc[7] = fmaf(p1.w, xv, acc[7]);
    }
    unsigned short* Y = (unsigned short*)ws_y;
    #pragma unroll
    for (int h = 0; h < NH; ++h)
      Y[(size_t)b * 4096 + h * 512 + t] = f2bf(acc[h]);
  }
}

// ================= KS: S partials via K-split. grid 256 = bt(4) x et(8) x sl(8) =================
// Spart[sl][b][e] = sum_{k in slice sl} Y[b][k] * Pt[e][k]   (f32, overlays Mt region)
__global__ __launch_bounds__(512, 2)
void ks_s(const char* __restrict__ ws_y, const char* __restrict__ ws_pt,
          float* __restrict__ Spart) {
  extern __shared__ char sm[];
  char* At = sm;
  char* Bt = sm + 65536;
  const int t = threadIdx.x, lane = t & 63, wave = t >> 6;
  const int bt = blockIdx.x >> 6, et = (blockIdx.x >> 3) & 7, sl = blockIdx.x & 7;
  const int b0 = bt * 64, e0 = et * 64;
  const size_t kb2 = (size_t)sl * 1024;  // byte offset of this K-slice (512 bf16)

  #pragma unroll
  for (int i = 0; i < 8; ++i) {
    const int r = wave * 8 + i;
    const int byt = (16 * (lane & 7)) ^ ((r & 7) << 4);
    uint4 va = ((const uint4*)(ws_y + (size_t)(b0 + r) * 8192 + kb2))[lane];
    *(uint4*)(At + (lane >> 3) * 8192 + r * 128 + byt) = va;
    uint4 vb = ((const uint4*)(ws_pt + (size_t)(e0 + r) * 8192 + kb2))[lane];
    *(uint4*)(Bt + (lane >> 3) * 8192 + r * 128 + byt) = vb;
  }
  __syncthreads();

  const int lo = ((lane & 15) * 128) + (((lane >> 4) * 16) ^ ((lane & 7) << 4));
  const int hi = ((lane & 15) * 128) + ((((lane >> 4) * 16) + 64) ^ ((lane & 7) << 4));
  const int bsub = wave & 3, epair = wave >> 2;

  f32x4 c0 = {0.f, 0.f, 0.f, 0.f}, c1 = {0.f, 0.f, 0.f, 0.f};
  #pragma unroll
  for (int kc = 0; kc < 8; ++kc) {
    const char* ab = At + kc * 8192 + bsub * 2048;
    bf16x8 aL = *(const bf16x8*)(ab + lo);
    bf16x8 aH = *(const bf16x8*)(ab + hi);
    const char* bb0 = Bt + kc * 8192 + (epair * 2) * 2048;
    const char* bb1 = bb0 + 2048;
    c0 = __builtin_amdgcn_mfma_f32_16x16x32_bf16(aL, *(const bf16x8*)(bb0 + lo), c0, 0, 0, 0);
    c0 = __builtin_amdgcn_mfma_f32_16x16x32_bf16(aH, *(const bf16x8*)(bb0 + hi), c0, 0, 0, 0);
    c1 = __builtin_amdgcn_mfma_f32_16x16x32_bf16(aL, *(const bf16x8*)(bb1 + lo), c1, 0, 0, 0);
    c1 = __builtin_amdgcn_mfma_f32_16x16x32_bf16(aH, *(const bf16x8*)(bb1 + hi), c1, 0, 0, 0);
  }
  const int brow = b0 + bsub * 16 + (lane >> 4) * 4;
  const int ec0 = e0 + (epair * 2) * 16 + (lane & 15);
  #pragma unroll
  for (int r = 0; r < 4; ++r) {
    Spart[((size_t)sl * 256 + brow + r) * 512 + ec0] = c0[r];
    Spart[((size_t)sl * 256 + brow + r) * 512 + ec0 + 16] = c1[r];
  }
}

// ================= K4: spectral phase — two-pass chunked softmax =================
#define K4_LDS 141312
__global__ __launch_bounds__(512, 2)
void k4_spec(const float* __restrict__ x, const char* __restrict__ Cws,
             const float* __restrict__ Spart, const float* __restrict__ bout,
             float* __restrict__ out) {
  extern __shared__ char smem[];
  char* xTc = smem;
  char* w2Tc = smem + 65536;
  char* Cc = smem + 131072;
  float* s_l = (float*)(smem + 139264);

  const int t = threadIdx.x;
  const int lane = t & 63;
  const int wave = t >> 6;
  const int b = blockIdx.x;
  const float* xb = x + (size_t)b * NP * DIM;

  const int lo_off = ((lane & 15) * 128) + ((((lane >> 4) * 16)) ^ ((lane & 7) << 4));
  const int hi_off = ((lane & 15) * 128) + ((((lane >> 4) * 16) + 64) ^ ((lane & 7) << 4));

  {
    const int d = t;
    #pragma unroll
    for (int c = 0; c < 8; ++c) {
      float v0 = xb[(c * 8 + 0) * DIM + d];
      float v1 = xb[(c * 8 + 1) * DIM + d];
      float v2 = xb[(c * 8 + 2) * DIM + d];
      float v3 = xb[(c * 8 + 3) * DIM + d];
      float v4 = xb[(c * 8 + 4) * DIM + d];
      float v5 = xb[(c * 8 + 5) * DIM + d];
      float v6 = xb[(c * 8 + 6) * DIM + d];
      float v7 = xb[(c * 8 + 7) * DIM + d];
      uint4 pk;
      pk.x = pk2(v0, v1);
      pk.y = pk2(v2, v3);
      pk.z = pk2(v4, v5);
      pk.w = pk2(v6, v7);
      *(uint4*)(xTc + d * 128 + ((c * 16) ^ ((d & 7) << 4))) = pk;
    }
    ((uint4*)Cc)[t] = ((const uint4*)Cws)[t];
    // s_l = bout + sum of 8 K-slice partials
    float sacc = bout[t];
    #pragma unroll
    for (int sl = 0; sl < 8; ++sl)
      sacc += Spart[((size_t)sl * 256 + b) * 512 + t];
    s_l[t] = sacc;
  }
  __syncthreads();

  // W2-MFMA: W2[m][e] = sum_mm C[m][mm] * x[mm][e]; write w2T[e][m] bf16 swizzled
  {
    bf16x8 af0[4], af1[4];
    #pragma unroll
    for (int mt = 0; mt < 4; ++mt) {
      af0[mt] = *(const bf16x8*)(Cc + mt * 16 * 128 + lo_off);
      af1[mt] = *(const bf16x8*)(Cc + mt * 16 * 128 + hi_off);
    }
    #pragma unroll
    for (int etl = 0; etl < 4; ++etl) {
      const int e0 = (wave * 4 + etl) * 16;
      bf16x8 b0 = *(const bf16x8*)(xTc + e0 * 128 + lo_off);
      bf16x8 b1 = *(const bf16x8*)(xTc + e0 * 128 + hi_off);
      #pragma unroll
      for (int mt = 0; mt < 4; ++mt) {
        f32x4 c = {0.f, 0.f, 0.f, 0.f};
        c = __builtin_amdgcn_mfma_f32_16x16x32_bf16(af0[mt], b0, c, 0, 0, 0);
        c = __builtin_amdgcn_mfma_f32_16x16x32_bf16(af1[mt], b1, c, 0, 0, 0);
        const int e = e0 + (lane & 15);
        const int mrow = mt * 16 + (lane >> 4) * 4;
        uint2 pk;
        pk.x = pk2(c[0], c[1]);
        pk.y = pk2(c[2], c[3]);
        *(uint2*)(w2Tc + e * 128 + ((mrow * 2) ^ ((e & 7) << 4))) = pk;
      }
    }
  }
  __syncthreads();

  float treg[32];
  #pragma unroll
  for (int et = 0; et < 32; ++et) treg[et] = 0.f;

  for (int pass = 0; pass < 4; ++pass) {
    const int d0 = pass * 128 + wave * 16;
    bf16x8 a0 = *(const bf16x8*)(xTc + d0 * 128 + lo_off);
    bf16x8 a1 = *(const bf16x8*)(xTc + d0 * 128 + hi_off);

    float rs[4] = {0.f, 0.f, 0.f, 0.f};
    #pragma unroll 4
    for (int et = 0; et < 32; ++et) {
      bf16x8 b0 = *(const bf16x8*)(w2Tc + et * 2048 + lo_off);
      bf16x8 b1 = *(const bf16x8*)(w2Tc + et * 2048 + hi_off);
      f32x4 c = {0.f, 0.f, 0.f, 0.f};
      c = __builtin_amdgcn_mfma_f32_16x16x32_bf16(a0, b0, c, 0, 0, 0);
      c = __builtin_amdgcn_mfma_f32_16x16x32_bf16(a1, b1, c, 0, 0, 0);
      rs[0] += __expf(c[0]);
      rs[1] += __expf(c[1]);
      rs[2] += __expf(c[2]);
      rs[3] += __expf(c[3]);
    }
    #pragma unroll
    for (int r = 0; r < 4; ++r) {
      rs[r] += __shfl_xor(rs[r], 1);
      rs[r] += __shfl_xor(rs[r], 2);
      rs[r] += __shfl_xor(rs[r], 4);
      rs[r] += __shfl_xor(rs[r], 8);
    }
    float coef[4];
    #pragma unroll
    for (int r = 0; r < 4; ++r)
      coef[r] = s_l[d0 + (lane >> 4) * 4 + r] / rs[r];

    #pragma unroll 4
    for (int et = 0; et < 32; ++et) {
      bf16x8 b0 = *(const bf16x8*)(w2Tc + et * 2048 + lo_off);
      bf16x8 b1 = *(const bf16x8*)(w2Tc + et * 2048 + hi_off);
      f32x4 c = {0.f, 0.f, 0.f, 0.f};
      c = __builtin_amdgcn_mfma_f32_16x16x32_bf16(a0, b0, c, 0, 0, 0);
      c = __builtin_amdgcn_mfma_f32_16x16x32_bf16(a1, b1, c, 0, 0, 0);
      float tp = treg[et];
      tp = fmaf(coef[0], __expf(c[0]), tp);
      tp = fmaf(coef[1], __expf(c[1]), tp);
      tp = fmaf(coef[2], __expf(c[2]), tp);
      tp = fmaf(coef[3], __expf(c[3]), tp);
      treg[et] = tp;
    }
  }
  __syncthreads();

  #pragma unroll
  for (int et = 0; et < 32; ++et) {
    treg[et] += __shfl_xor(treg[et], 16);
    treg[et] += __shfl_xor(treg[et], 32);
  }
  float* wpart = (float*)xTc;  // [8][512]
  if (lane < 16) {
    #pragma unroll
    for (int et = 0; et < 32; ++et)
      wpart[wave * 512 + et * 16 + lane] = treg[et];
  }
  __syncthreads();

  float tf = 0.f;
  #pragma unroll
  for (int w = 0; w < 8; ++w) tf += wpart[w * 512 + t];

  float* ob = out + (size_t)b * NP * DIM + t;
  #pragma unroll 4
  for (int n = 0; n < NP; ++n) ob[n * DIM] = tf;
}

extern "C" void kernel_launch(void* const* d_in, const int* in_sizes, int n_in,
                              void* d_out, int out_size, void* d_ws, size_t ws_size,
                              hipStream_t stream) {
  (void)in_sizes; (void)n_in; (void)out_size; (void)ws_size;
  const float* x     = (const float*)d_in[0];
  const float* Wq    = (const float*)d_in[1];
  const float* Wkv   = (const float*)d_in[2];
  const float* Wout  = (const float*)d_in[3];
  const float* bout  = (const float*)d_in[4];
  const float* Wspec = (const float*)d_in[5];
  float* out = (float*)d_out;

  char* ws = (char*)d_ws;

  hipFuncSetAttribute(reinterpret_cast<const void*>(ku_u),
                      hipFuncAttributeMaxDynamicSharedMemorySize, GEMM_LDS);
  hipFuncSetAttribute(reinterpret_cast<const void*>(ks_s),
                      hipFuncAttributeMaxDynamicSharedMemorySize, GEMM_LDS);
  hipFuncSetAttribute(reinterpret_cast<const void*>(k4_spec),
                      hipFuncAttributeMaxDynamicSharedMemorySize, K4_LDS);

  kw_prep<<<dim3(1025), dim3(512), 0, stream>>>(Wq, Wkv, Wout, Wspec, ws);
  ku_u   <<<dim3(256),  dim3(512), GEMM_LDS, stream>>>(x, ws, ws + WS_U);
  k2_attn<<<dim3(256),  dim3(512), 0, stream>>>(x, ws + WS_U, ws + WS_Y);
  ks_s   <<<dim3(256),  dim3(512), GEMM_LDS, stream>>>(ws + WS_Y, ws + WS_PT,
                                                       (float*)(ws + WS_MT));
  k4_spec<<<dim3(256),  dim3(512), K4_LDS, stream>>>(x, ws, (const float*)(ws + WS_MT),
                                                     bout, out);
}

// Round 9
// 114.123 us; speedup vs baseline: 3.6003x; 1.0202x over previous
//
#include <hip/hip_runtime.h>

#define NP 64
#define DIM 512
#define NH 8
#define SCALE 0.125f

typedef __attribute__((ext_vector_type(4))) float f32x4;
typedef __attribute__((ext_vector_type(8))) short bf16x8;

// ---------------- workspace layout (bytes), high-water ~12.6 MB ----------------
// WS_MT region is reused: Mt (kw->ku) then f32 Spart[8][256][512] (ks->k4).
#define WS_C   0                 // bf16 C[64][64] swizzled (8 KB)
#define WS_MT  8192              // bf16 Mt[4096][512] (4 MB) -> f32 Spart (4 MB)
#define WS_PT  4202496           // bf16 Pt[512 e][4096 K=(h,d)]    (4 MB)
#define WS_U   8396800           // bf16 U[256 b][4096 n=(h,e)]     (2 MB)
#define WS_Y   10493952          // bf16 Y[256 b][4096 K=(h,d)]     (2 MB)

static __device__ __forceinline__ unsigned short f2bf(float f) {
  unsigned int u = __builtin_bit_cast(unsigned int, f);
  u += 0x7fffu + ((u >> 16) & 1u);
  return (unsigned short)(u >> 16);
}
static __device__ __forceinline__ float bf2f(unsigned short s) {
  return __builtin_bit_cast(float, ((unsigned int)s) << 16);
}
static __device__ __forceinline__ unsigned pk2(float a, float b) {
  return (unsigned)f2bf(a) | ((unsigned)f2bf(b) << 16);
}

// ================= KW: batch-independent precompute =================
__global__ __launch_bounds__(512)
void kw_prep(const float* __restrict__ Wq, const float* __restrict__ Wkv,
             const float* __restrict__ Wout, const float* __restrict__ Wspec,
             char* __restrict__ ws) {
  __shared__ float wa[64 * 65];
  __shared__ float wb[64 * 65];
  const int t = threadIdx.x;
  const int blk = blockIdx.x;
  const int sr = t >> 3, sc8 = (t & 7) * 8;

  if (blk == 1024) {
    #pragma unroll
    for (int cc = 0; cc < 8; ++cc) {
      wa[sr * 65 + sc8 + cc] = Wspec[sr * 192 + sc8 + cc];
      wb[sr * 65 + sc8 + cc] = Wspec[sr * 192 + 64 + sc8 + cc];
    }
    __syncthreads();
    const int m = sr, mm0 = sc8;
    float acc[8] = {0.f, 0.f, 0.f, 0.f, 0.f, 0.f, 0.f, 0.f};
    for (int n = 0; n < 64; ++n) {
      float qv = wa[m * 65 + n];
      #pragma unroll
      for (int j = 0; j < 8; ++j)
        acc[j] = fmaf(qv, wb[(mm0 + j) * 65 + n], acc[j]);
    }
    uint4 pk;
    pk.x = pk2(acc[0] * SCALE, acc[1] * SCALE);
    pk.y = pk2(acc[2] * SCALE, acc[3] * SCALE);
    pk.z = pk2(acc[4] * SCALE, acc[5] * SCALE);
    pk.w = pk2(acc[6] * SCALE, acc[7] * SCALE);
    *(uint4*)(ws + WS_C + m * 128 + ((mm0 * 2) ^ ((m & 7) << 4))) = pk;
    return;
  }

  const bool isP = blk >= 512;
  const int id = blk & 511;
  const int h = id >> 6, et = (id >> 3) & 7, dt = id & 7;

  const float* sa = isP ? (Wkv + (size_t)(dt * 64 + sr) * 1024 + 512 + h * 64)
                        : (Wq + (size_t)(dt * 64 + sr) * 512 + h * 64);
  const float* sb = isP ? (Wout + (size_t)(h * 64 + sr) * 512 + et * 64)
                        : (Wkv + (size_t)(et * 64 + sr) * 1024 + h * 64);
  {
    float4 a0 = *(const float4*)(sa + sc8), a1 = *(const float4*)(sa + sc8 + 4);
    float* d = wa + sr * 65 + sc8;
    d[0] = a0.x; d[1] = a0.y; d[2] = a0.z; d[3] = a0.w;
    d[4] = a1.x; d[5] = a1.y; d[6] = a1.z; d[7] = a1.w;
    float4 b0 = *(const float4*)(sb + sc8), b1 = *(const float4*)(sb + sc8 + 4);
    float* e = wb + sr * 65 + sc8;
    e[0] = b0.x; e[1] = b0.y; e[2] = b0.z; e[3] = b0.w;
    e[4] = b1.x; e[5] = b1.y; e[6] = b1.z; e[7] = b1.w;
  }
  __syncthreads();

  const int er = sr, dc8 = sc8;
  float acc[8] = {0.f, 0.f, 0.f, 0.f, 0.f, 0.f, 0.f, 0.f};
  if (!isP) {
    for (int j = 0; j < 64; ++j) {
      float bv = wb[er * 65 + j];
      #pragma unroll
      for (int dd = 0; dd < 8; ++dd)
        acc[dd] = fmaf(bv, wa[(dc8 + dd) * 65 + j], acc[dd]);
    }
  } else {
    for (int j = 0; j < 64; ++j) {
      float bv = wb[j * 65 + er];
      #pragma unroll
      for (int dd = 0; dd < 8; ++dd)
        acc[dd] = fmaf(bv, wa[(dc8 + dd) * 65 + j], acc[dd]);
    }
  }
  uint4 pk;
  pk.x = pk2(acc[0], acc[1]);
  pk.y = pk2(acc[2], acc[3]);
  pk.z = pk2(acc[4], acc[5]);
  pk.w = pk2(acc[6], acc[7]);
  if (!isP)
    *(uint4*)(ws + WS_MT + ((size_t)(h * 512 + et * 64 + er) * 512 + dt * 64 + dc8) * 2) = pk;
  else
    *(uint4*)(ws + WS_PT + ((size_t)(et * 64 + er) * 4096 + h * 512 + dt * 64 + dc8) * 2) = pk;
}

// ================= KU: U[256][4096] = XC[256][512] @ Mt^T (bf16 MFMA) =================
#define GEMM_LDS 131072
__global__ __launch_bounds__(512, 2)
void ku_u(const float* __restrict__ x, const char* __restrict__ ws,
          char* __restrict__ ws_u) {
  extern __shared__ char sm[];
  char* At = sm;
  char* Bt = sm + 65536;
  const int t = threadIdx.x, lane = t & 63, wave = t >> 6;
  const int bt = blockIdx.x >> 6, nt = blockIdx.x & 63;
  const int b0 = bt * 64, n0 = nt * 64;
  const char* Mt = ws + WS_MT;

  #pragma unroll
  for (int i = 0; i < 8; ++i) {
    const int r = wave * 8 + i;
    const float4* xr = (const float4*)(x + ((size_t)(b0 + r) * 64 + 32) * 512);
    float4 a = xr[lane], c = xr[64 + lane];
    uint2 pa = {pk2(a.x, a.y), pk2(a.z, a.w)};
    uint2 pc = {pk2(c.x, c.y), pk2(c.z, c.w)};
    const int swz = (r & 7) << 4;
    const int byt = (8 * (lane & 15)) ^ swz;
    *(uint2*)(At + (lane >> 4) * 8192 + r * 128 + byt) = pa;
    *(uint2*)(At + (4 + (lane >> 4)) * 8192 + r * 128 + byt) = pc;
  }
  #pragma unroll
  for (int i = 0; i < 8; ++i) {
    const int r = wave * 8 + i;
    uint4 v = ((const uint4*)(Mt + (size_t)(n0 + r) * 1024))[lane];
    *(uint4*)(Bt + (lane >> 3) * 8192 + r * 128 + ((16 * (lane & 7)) ^ ((r & 7) << 4))) = v;
  }
  __syncthreads();

  const int lo = ((lane & 15) * 128) + (((lane >> 4) * 16) ^ ((lane & 7) << 4));
  const int hi = ((lane & 15) * 128) + ((((lane >> 4) * 16) + 64) ^ ((lane & 7) << 4));
  const int bsub = wave & 3, npair = wave >> 2;

  f32x4 c0 = {0.f, 0.f, 0.f, 0.f}, c1 = {0.f, 0.f, 0.f, 0.f};
  #pragma unroll
  for (int kc = 0; kc < 8; ++kc) {
    const char* ab = At + kc * 8192 + bsub * 2048;
    bf16x8 aL = *(const bf16x8*)(ab + lo);
    bf16x8 aH = *(const bf16x8*)(ab + hi);
    const char* bb0 = Bt + kc * 8192 + (npair * 2) * 2048;
    const char* bb1 = bb0 + 2048;
    c0 = __builtin_amdgcn_mfma_f32_16x16x32_bf16(aL, *(const bf16x8*)(bb0 + lo), c0, 0, 0, 0);
    c0 = __builtin_amdgcn_mfma_f32_16x16x32_bf16(aH, *(const bf16x8*)(bb0 + hi), c0, 0, 0, 0);
    c1 = __builtin_amdgcn_mfma_f32_16x16x32_bf16(aL, *(const bf16x8*)(bb1 + lo), c1, 0, 0, 0);
    c1 = __builtin_amdgcn_mfma_f32_16x16x32_bf16(aH, *(const bf16x8*)(bb1 + hi), c1, 0, 0, 0);
  }
  unsigned short* U = (unsigned short*)ws_u;
  const int brow = b0 + bsub * 16 + (lane >> 4) * 4;
  const int nc0 = n0 + (npair * 2) * 16 + (lane & 15);
  #pragma unroll
  for (int r = 0; r < 4; ++r) {
    U[(size_t)(brow + r) * 4096 + nc0] = f2bf(c0[r]);
    U[(size_t)(brow + r) * 4096 + nc0 + 16] = f2bf(c1[r]);
  }
}

// ================= K2: batch-local spatial attention =================
__global__ __launch_bounds__(512)
void k2_attn(const float* __restrict__ x, const char* __restrict__ ws_u,
             char* __restrict__ ws_y) {
  __shared__ float ul[8 * 512];
  __shared__ float scoreL[8 * 64];
  __shared__ float pT[64 * 8];
  const int t = threadIdx.x;
  const int lane = t & 63;
  const int wave = t >> 6;
  const int b = blockIdx.x;
  const float* xb = x + (size_t)b * NP * DIM;

  {
    uint4 v = ((const uint4*)(ws_u + (size_t)b * 8192))[t];
    const unsigned short* pv = (const unsigned short*)&v;
    float* d = ul + t * 8;
    #pragma unroll
    for (int g = 0; g < 8; ++g) d[g] = bf2f(pv[g]);
  }
  __syncthreads();

  {
    float4 uf0[8], uf1[8];
    #pragma unroll
    for (int h = 0; h < 8; ++h) {
      uf0[h] = *(const float4*)(ul + h * 512 + 4 * lane);
      uf1[h] = *(const float4*)(ul + h * 512 + 256 + 4 * lane);
    }
    #pragma unroll 2
    for (int i = 0; i < 8; ++i) {
      const int m = wave * 8 + i;
      const float4* xr = (const float4*)(xb + (size_t)m * DIM);
      float4 xv0 = xr[lane];
      float4 xv1 = xr[64 + lane];
      #pragma unroll
      for (int h = 0; h < 8; ++h) {
        float p = xv0.x * uf0[h].x + xv0.y * uf0[h].y + xv0.z * uf0[h].z + xv0.w * uf0[h].w
                + xv1.x * uf1[h].x + xv1.y * uf1[h].y + xv1.z * uf1[h].z + xv1.w * uf1[h].w;
        p += __shfl_xor(p, 1);
        p += __shfl_xor(p, 2);
        p += __shfl_xor(p, 4);
        p += __shfl_xor(p, 8);
        p += __shfl_xor(p, 16);
        p += __shfl_xor(p, 32);
        if (lane == 0) scoreL[h * 64 + m] = p;
      }
    }
  }
  __syncthreads();

  {
    float sc = scoreL[wave * 64 + lane] * SCALE;
    float mx = sc;
    #pragma unroll
    for (int off = 32; off > 0; off >>= 1)
      mx = fmaxf(mx, __shfl_xor(mx, off));
    float ev = __expf(sc - mx);
    float sm = ev;
    #pragma unroll
    for (int off = 32; off > 0; off >>= 1)
      sm += __shfl_xor(sm, off);
    pT[lane * NH + wave] = ev / sm;
  }
  __syncthreads();

  {
    float acc[NH];
    #pragma unroll
    for (int h = 0; h < NH; ++h) acc[h] = 0.f;
    #pragma unroll 2
    for (int m = 0; m < NP; ++m) {
      float xv = xb[(size_t)m * DIM + t];
      const float4* pp = (const float4*)(pT + m * NH);
      float4 p0 = pp[0], p1 = pp[1];
      acc[0] = fmaf(p0.x, xv, acc[0]);
      acc[1] = fmaf(p0.y, xv, acc[1]);
      acc[2] = fmaf(p0.z, xv, acc[2]);
      acc[3] = fmaf(p0.w, xv, acc[3]);
      acc[4] = fmaf(p1.x, xv, acc[4]);
      acc[5] = fmaf(p1.y, xv, acc[5]);
      acc[6] = fmaf(p1.z, xv, acc[6]);
      acc[7] = fmaf(p1.w, xv, acc[7]);
    }
    unsigned short* Y = (unsigned short*)ws_y;
    #pragma unroll
    for (int h = 0; h < NH; ++h)
      Y[(size_t)b * 4096 + h * 512 + t] = f2bf(acc[h]);
  }
}

// ================= KS: S partials via K-split. grid 256 = bt(4) x et(8) x sl(8) =================
__global__ __launch_bounds__(512, 2)
void ks_s(const char* __restrict__ ws_y, const char* __restrict__ ws_pt,
          float* __restrict__ Spart) {
  extern __shared__ char sm[];
  char* At = sm;
  char* Bt = sm + 65536;
  const int t = threadIdx.x, lane = t & 63, wave = t >> 6;
  const int bt = blockIdx.x >> 6, et = (blockIdx.x >> 3) & 7, sl = blockIdx.x & 7;
  const int b0 = bt * 64, e0 = et * 64;
  const size_t kb2 = (size_t)sl * 1024;

  #pragma unroll
  for (int i = 0; i < 8; ++i) {
    const int r = wave * 8 + i;
    const int byt = (16 * (lane & 7)) ^ ((r & 7) << 4);
    uint4 va = ((const uint4*)(ws_y + (size_t)(b0 + r) * 8192 + kb2))[lane];
    *(uint4*)(At + (lane >> 3) * 8192 + r * 128 + byt) = va;
    uint4 vb = ((const uint4*)(ws_pt + (size_t)(e0 + r) * 8192 + kb2))[lane];
    *(uint4*)(Bt + (lane >> 3) * 8192 + r * 128 + byt) = vb;
  }
  __syncthreads();

  const int lo = ((lane & 15) * 128) + (((lane >> 4) * 16) ^ ((lane & 7) << 4));
  const int hi = ((lane & 15) * 128) + ((((lane >> 4) * 16) + 64) ^ ((lane & 7) << 4));
  const int bsub = wave & 3, epair = wave >> 2;

  f32x4 c0 = {0.f, 0.f, 0.f, 0.f}, c1 = {0.f, 0.f, 0.f, 0.f};
  #pragma unroll
  for (int kc = 0; kc < 8; ++kc) {
    const char* ab = At + kc * 8192 + bsub * 2048;
    bf16x8 aL = *(const bf16x8*)(ab + lo);
    bf16x8 aH = *(const bf16x8*)(ab + hi);
    const char* bb0 = Bt + kc * 8192 + (epair * 2) * 2048;
    const char* bb1 = bb0 + 2048;
    c0 = __builtin_amdgcn_mfma_f32_16x16x32_bf16(aL, *(const bf16x8*)(bb0 + lo), c0, 0, 0, 0);
    c0 = __builtin_amdgcn_mfma_f32_16x16x32_bf16(aH, *(const bf16x8*)(bb0 + hi), c0, 0, 0, 0);
    c1 = __builtin_amdgcn_mfma_f32_16x16x32_bf16(aL, *(const bf16x8*)(bb1 + lo), c1, 0, 0, 0);
    c1 = __builtin_amdgcn_mfma_f32_16x16x32_bf16(aH, *(const bf16x8*)(bb1 + hi), c1, 0, 0, 0);
  }
  const int brow = b0 + bsub * 16 + (lane >> 4) * 4;
  const int ec0 = e0 + (epair * 2) * 16 + (lane & 15);
  #pragma unroll
  for (int r = 0; r < 4; ++r) {
    Spart[((size_t)sl * 256 + brow + r) * 512 + ec0] = c0[r];
    Spart[((size_t)sl * 256 + brow + r) * 512 + ec0 + 16] = c1[r];
  }
}

// ================= K4: spectral phase — LDS-diet (74 KB -> 2 blocks/CU) =================
// region0 [0,65536): xT (stage+W2) then w2T (phase C) then wpart (final reduce)
// Cc [65536,73728) ; s_l [73728,75776)
#define K4_LDS 75776
__global__ __launch_bounds__(512, 2)
void k4_spec(const float* __restrict__ x, const char* __restrict__ Cws,
             const float* __restrict__ Spart, const float* __restrict__ bout,
             float* __restrict__ out) {
  extern __shared__ char smem[];
  char* region0 = smem;
  char* Cc = smem + 65536;
  float* s_l = (float*)(smem + 73728);

  const int t = threadIdx.x;
  const int lane = t & 63;
  const int wave = t >> 6;
  const int b = blockIdx.x;
  const float* xb = x + (size_t)b * NP * DIM;

  const int lo_off = ((lane & 15) * 128) + ((((lane >> 4) * 16)) ^ ((lane & 7) << 4));
  const int hi_off = ((lane & 15) * 128) + ((((lane >> 4) * 16) + 64) ^ ((lane & 7) << 4));

  // ---- stage xT (bf16, swizzled) into region0; C; s_l ----
  {
    const int d = t;
    #pragma unroll
    for (int c = 0; c < 8; ++c) {
      float v0 = xb[(c * 8 + 0) * DIM + d];
      float v1 = xb[(c * 8 + 1) * DIM + d];
      float v2 = xb[(c * 8 + 2) * DIM + d];
      float v3 = xb[(c * 8 + 3) * DIM + d];
      float v4 = xb[(c * 8 + 4) * DIM + d];
      float v5 = xb[(c * 8 + 5) * DIM + d];
      float v6 = xb[(c * 8 + 6) * DIM + d];
      float v7 = xb[(c * 8 + 7) * DIM + d];
      uint4 pk;
      pk.x = pk2(v0, v1);
      pk.y = pk2(v2, v3);
      pk.z = pk2(v4, v5);
      pk.w = pk2(v6, v7);
      *(uint4*)(region0 + d * 128 + ((c * 16) ^ ((d & 7) << 4))) = pk;
    }
    ((uint4*)Cc)[t] = ((const uint4*)Cws)[t];
    float sacc = bout[t];
    #pragma unroll
    for (int sl = 0; sl < 8; ++sl)
      sacc += Spart[((size_t)sl * 256 + b) * 512 + t];
    s_l[t] = sacc;
  }
  __syncthreads();

  // ---- load phase-C A-fragments (all 4 passes) into registers ----
  bf16x8 pa0[4], pa1[4];
  #pragma unroll
  for (int pass = 0; pass < 4; ++pass) {
    const int d0 = pass * 128 + wave * 16;
    pa0[pass] = *(const bf16x8*)(region0 + d0 * 128 + lo_off);
    pa1[pass] = *(const bf16x8*)(region0 + d0 * 128 + hi_off);
  }

  // ---- W2-MFMA into packed registers (region0 still = xT) ----
  uint2 pkW2[4][4];  // [etl][mt]
  {
    bf16x8 af0[4], af1[4];
    #pragma unroll
    for (int mt = 0; mt < 4; ++mt) {
      af0[mt] = *(const bf16x8*)(Cc + mt * 16 * 128 + lo_off);
      af1[mt] = *(const bf16x8*)(Cc + mt * 16 * 128 + hi_off);
    }
    #pragma unroll
    for (int etl = 0; etl < 4; ++etl) {
      const int e0 = (wave * 4 + etl) * 16;
      bf16x8 b0 = *(const bf16x8*)(region0 + e0 * 128 + lo_off);
      bf16x8 b1 = *(const bf16x8*)(region0 + e0 * 128 + hi_off);
      #pragma unroll
      for (int mt = 0; mt < 4; ++mt) {
        f32x4 c = {0.f, 0.f, 0.f, 0.f};
        c = __builtin_amdgcn_mfma_f32_16x16x32_bf16(af0[mt], b0, c, 0, 0, 0);
        c = __builtin_amdgcn_mfma_f32_16x16x32_bf16(af1[mt], b1, c, 0, 0, 0);
        pkW2[etl][mt].x = pk2(c[0], c[1]);
        pkW2[etl][mt].y = pk2(c[2], c[3]);
      }
    }
  }
  __syncthreads();  // all waves done reading xT

  // ---- write w2T (bf16, swizzled) into region0, overwriting xT ----
  {
    #pragma unroll
    for (int etl = 0; etl < 4; ++etl) {
      const int e = (wave * 4 + etl) * 16 + (lane & 15);
      #pragma unroll
      for (int mt = 0; mt < 4; ++mt) {
        const int mrow = mt * 16 + (lane >> 4) * 4;
        *(uint2*)(region0 + e * 128 + ((mrow * 2) ^ ((e & 7) << 4))) = pkW2[etl][mt];
      }
    }
  }
  __syncthreads();

  // ---- phase C: two-pass chunked softmax; A-frags from regs, w2T from region0 ----
  float treg[32];
  #pragma unroll
  for (int et = 0; et < 32; ++et) treg[et] = 0.f;

  #pragma unroll
  for (int pass = 0; pass < 4; ++pass) {
    const int d0 = pass * 128 + wave * 16;
    bf16x8 a0 = pa0[pass];
    bf16x8 a1 = pa1[pass];

    float rs[4] = {0.f, 0.f, 0.f, 0.f};
    #pragma unroll 4
    for (int et = 0; et < 32; ++et) {
      bf16x8 b0 = *(const bf16x8*)(region0 + et * 2048 + lo_off);
      bf16x8 b1 = *(const bf16x8*)(region0 + et * 2048 + hi_off);
      f32x4 c = {0.f, 0.f, 0.f, 0.f};
      c = __builtin_amdgcn_mfma_f32_16x16x32_bf16(a0, b0, c, 0, 0, 0);
      c = __builtin_amdgcn_mfma_f32_16x16x32_bf16(a1, b1, c, 0, 0, 0);
      rs[0] += __expf(c[0]);
      rs[1] += __expf(c[1]);
      rs[2] += __expf(c[2]);
      rs[3] += __expf(c[3]);
    }
    #pragma unroll
    for (int r = 0; r < 4; ++r) {
      rs[r] += __shfl_xor(rs[r], 1);
      rs[r] += __shfl_xor(rs[r], 2);
      rs[r] += __shfl_xor(rs[r], 4);
      rs[r] += __shfl_xor(rs[r], 8);
    }
    float coef[4];
    #pragma unroll
    for (int r = 0; r < 4; ++r)
      coef[r] = s_l[d0 + (lane >> 4) * 4 + r] / rs[r];

    #pragma unroll 4
    for (int et = 0; et < 32; ++et) {
      bf16x8 b0 = *(const bf16x8*)(region0 + et * 2048 + lo_off);
      bf16x8 b1 = *(const bf16x8*)(region0 + et * 2048 + hi_off);
      f32x4 c = {0.f, 0.f, 0.f, 0.f};
      c = __builtin_amdgcn_mfma_f32_16x16x32_bf16(a0, b0, c, 0, 0, 0);
      c = __builtin_amdgcn_mfma_f32_16x16x32_bf16(a1, b1, c, 0, 0, 0);
      float tp = treg[et];
      tp = fmaf(coef[0], __expf(c[0]), tp);
      tp = fmaf(coef[1], __expf(c[1]), tp);
      tp = fmaf(coef[2], __expf(c[2]), tp);
      tp = fmaf(coef[3], __expf(c[3]), tp);
      treg[et] = tp;
    }
  }
  __syncthreads();  // done reading w2T; region0 becomes partial buffer

  #pragma unroll
  for (int et = 0; et < 32; ++et) {
    treg[et] += __shfl_xor(treg[et], 16);
    treg[et] += __shfl_xor(treg[et], 32);
  }
  float* wpart = (float*)region0;  // [8][512]
  if (lane < 16) {
    #pragma unroll
    for (int et = 0; et < 32; ++et)
      wpart[wave * 512 + et * 16 + lane] = treg[et];
  }
  __syncthreads();

  float tf = 0.f;
  #pragma unroll
  for (int w = 0; w < 8; ++w) tf += wpart[w * 512 + t];

  float* ob = out + (size_t)b * NP * DIM + t;
  #pragma unroll 4
  for (int n = 0; n < NP; ++n) ob[n * DIM] = tf;
}

extern "C" void kernel_launch(void* const* d_in, const int* in_sizes, int n_in,
                              void* d_out, int out_size, void* d_ws, size_t ws_size,
                              hipStream_t stream) {
  (void)in_sizes; (void)n_in; (void)out_size; (void)ws_size;
  const float* x     = (const float*)d_in[0];
  const float* Wq    = (const float*)d_in[1];
  const float* Wkv   = (const float*)d_in[2];
  const float* Wout  = (const float*)d_in[3];
  const float* bout  = (const float*)d_in[4];
  const float* Wspec = (const float*)d_in[5];
  float* out = (float*)d_out;

  char* ws = (char*)d_ws;

  hipFuncSetAttribute(reinterpret_cast<const void*>(ku_u),
                      hipFuncAttributeMaxDynamicSharedMemorySize, GEMM_LDS);
  hipFuncSetAttribute(reinterpret_cast<const void*>(ks_s),
                      hipFuncAttributeMaxDynamicSharedMemorySize, GEMM_LDS);
  hipFuncSetAttribute(reinterpret_cast<const void*>(k4_spec),
                      hipFuncAttributeMaxDynamicSharedMemorySize, K4_LDS);

  kw_prep<<<dim3(1025), dim3(512), 0, stream>>>(Wq, Wkv, Wout, Wspec, ws);
  ku_u   <<<dim3(256),  dim3(512), GEMM_LDS, stream>>>(x, ws, ws + WS_U);
  k2_attn<<<dim3(256),  dim3(512), 0, stream>>>(x, ws + WS_U, ws + WS_Y);
  ks_s   <<<dim3(256),  dim3(512), GEMM_LDS, stream>>>(ws + WS_Y, ws + WS_PT,
                                                       (float*)(ws + WS_MT));
  k4_spec<<<dim3(256),  dim3(512), K4_LDS, stream>>>(x, ws, (const float*)(ws + WS_MT),
                                                     bout, out);
}

// Round 10
// 111.969 us; speedup vs baseline: 3.6695x; 1.0192x over previous
//
#include <hip/hip_runtime.h>

#define NP 64
#define DIM 512
#define NH 8
#define SCALE 0.125f

typedef __attribute__((ext_vector_type(4))) float f32x4;
typedef __attribute__((ext_vector_type(8))) short bf16x8;

// ---------------- workspace layout (bytes), high-water ~12.6 MB ----------------
#define WS_C   0                 // bf16 C[64][64] swizzled (8 KB)
#define WS_MT  8192              // bf16 Mt[4096][512] (4 MB) -> f32 Spart (4 MB)
#define WS_PT  4202496           // bf16 Pt[512 e][4096 K=(h,d)]    (4 MB)
#define WS_U   8396800           // bf16 U[256 b][4096 n=(h,e)]     (2 MB)
#define WS_Y   10493952          // bf16 Y[256 b][4096 K=(h,d)]     (2 MB)

static __device__ __forceinline__ unsigned short f2bf(float f) {
  unsigned int u = __builtin_bit_cast(unsigned int, f);
  u += 0x7fffu + ((u >> 16) & 1u);
  return (unsigned short)(u >> 16);
}
static __device__ __forceinline__ float bf2f(unsigned short s) {
  return __builtin_bit_cast(float, ((unsigned int)s) << 16);
}
static __device__ __forceinline__ unsigned pk2(float a, float b) {
  return (unsigned)f2bf(a) | ((unsigned)f2bf(b) << 16);
}

// ================= KW: batch-independent precompute =================
__global__ __launch_bounds__(512)
void kw_prep(const float* __restrict__ Wq, const float* __restrict__ Wkv,
             const float* __restrict__ Wout, const float* __restrict__ Wspec,
             char* __restrict__ ws) {
  __shared__ float wa[64 * 65];
  __shared__ float wb[64 * 65];
  const int t = threadIdx.x;
  const int blk = blockIdx.x;
  const int sr = t >> 3, sc8 = (t & 7) * 8;

  if (blk == 1024) {
    #pragma unroll
    for (int cc = 0; cc < 8; ++cc) {
      wa[sr * 65 + sc8 + cc] = Wspec[sr * 192 + sc8 + cc];
      wb[sr * 65 + sc8 + cc] = Wspec[sr * 192 + 64 + sc8 + cc];
    }
    __syncthreads();
    const int m = sr, mm0 = sc8;
    float acc[8] = {0.f, 0.f, 0.f, 0.f, 0.f, 0.f, 0.f, 0.f};
    for (int n = 0; n < 64; ++n) {
      float qv = wa[m * 65 + n];
      #pragma unroll
      for (int j = 0; j < 8; ++j)
        acc[j] = fmaf(qv, wb[(mm0 + j) * 65 + n], acc[j]);
    }
    uint4 pk;
    pk.x = pk2(acc[0] * SCALE, acc[1] * SCALE);
    pk.y = pk2(acc[2] * SCALE, acc[3] * SCALE);
    pk.z = pk2(acc[4] * SCALE, acc[5] * SCALE);
    pk.w = pk2(acc[6] * SCALE, acc[7] * SCALE);
    *(uint4*)(ws + WS_C + m * 128 + ((mm0 * 2) ^ ((m & 7) << 4))) = pk;
    return;
  }

  const bool isP = blk >= 512;
  const int id = blk & 511;
  const int h = id >> 6, et = (id >> 3) & 7, dt = id & 7;

  const float* sa = isP ? (Wkv + (size_t)(dt * 64 + sr) * 1024 + 512 + h * 64)
                        : (Wq + (size_t)(dt * 64 + sr) * 512 + h * 64);
  const float* sb = isP ? (Wout + (size_t)(h * 64 + sr) * 512 + et * 64)
                        : (Wkv + (size_t)(et * 64 + sr) * 1024 + h * 64);
  {
    float4 a0 = *(const float4*)(sa + sc8), a1 = *(const float4*)(sa + sc8 + 4);
    float* d = wa + sr * 65 + sc8;
    d[0] = a0.x; d[1] = a0.y; d[2] = a0.z; d[3] = a0.w;
    d[4] = a1.x; d[5] = a1.y; d[6] = a1.z; d[7] = a1.w;
    float4 b0 = *(const float4*)(sb + sc8), b1 = *(const float4*)(sb + sc8 + 4);
    float* e = wb + sr * 65 + sc8;
    e[0] = b0.x; e[1] = b0.y; e[2] = b0.z; e[3] = b0.w;
    e[4] = b1.x; e[5] = b1.y; e[6] = b1.z; e[7] = b1.w;
  }
  __syncthreads();

  const int er = sr, dc8 = sc8;
  float acc[8] = {0.f, 0.f, 0.f, 0.f, 0.f, 0.f, 0.f, 0.f};
  if (!isP) {
    for (int j = 0; j < 64; ++j) {
      float bv = wb[er * 65 + j];
      #pragma unroll
      for (int dd = 0; dd < 8; ++dd)
        acc[dd] = fmaf(bv, wa[(dc8 + dd) * 65 + j], acc[dd]);
    }
  } else {
    for (int j = 0; j < 64; ++j) {
      float bv = wb[j * 65 + er];
      #pragma unroll
      for (int dd = 0; dd < 8; ++dd)
        acc[dd] = fmaf(bv, wa[(dc8 + dd) * 65 + j], acc[dd]);
    }
  }
  uint4 pk;
  pk.x = pk2(acc[0], acc[1]);
  pk.y = pk2(acc[2], acc[3]);
  pk.z = pk2(acc[4], acc[5]);
  pk.w = pk2(acc[6], acc[7]);
  if (!isP)
    *(uint4*)(ws + WS_MT + ((size_t)(h * 512 + et * 64 + er) * 512 + dt * 64 + dc8) * 2) = pk;
  else
    *(uint4*)(ws + WS_PT + ((size_t)(et * 64 + er) * 4096 + h * 512 + dt * 64 + dc8) * 2) = pk;
}

// ================= KU: U[256][4096] = XC[256][512] @ Mt^T (bf16 MFMA) =================
#define GEMM_LDS 131072
__global__ __launch_bounds__(512, 2)
void ku_u(const float* __restrict__ x, const char* __restrict__ ws,
          char* __restrict__ ws_u) {
  extern __shared__ char sm[];
  char* At = sm;
  char* Bt = sm + 65536;
  const int t = threadIdx.x, lane = t & 63, wave = t >> 6;
  const int bt = blockIdx.x >> 6, nt = blockIdx.x & 63;
  const int b0 = bt * 64, n0 = nt * 64;
  const char* Mt = ws + WS_MT;

  #pragma unroll
  for (int i = 0; i < 8; ++i) {
    const int r = wave * 8 + i;
    const float4* xr = (const float4*)(x + ((size_t)(b0 + r) * 64 + 32) * 512);
    float4 a = xr[lane], c = xr[64 + lane];
    uint2 pa = {pk2(a.x, a.y), pk2(a.z, a.w)};
    uint2 pc = {pk2(c.x, c.y), pk2(c.z, c.w)};
    const int swz = (r & 7) << 4;
    const int byt = (8 * (lane & 15)) ^ swz;
    *(uint2*)(At + (lane >> 4) * 8192 + r * 128 + byt) = pa;
    *(uint2*)(At + (4 + (lane >> 4)) * 8192 + r * 128 + byt) = pc;
  }
  #pragma unroll
  for (int i = 0; i < 8; ++i) {
    const int r = wave * 8 + i;
    uint4 v = ((const uint4*)(Mt + (size_t)(n0 + r) * 1024))[lane];
    *(uint4*)(Bt + (lane >> 3) * 8192 + r * 128 + ((16 * (lane & 7)) ^ ((r & 7) << 4))) = v;
  }
  __syncthreads();

  const int lo = ((lane & 15) * 128) + (((lane >> 4) * 16) ^ ((lane & 7) << 4));
  const int hi = ((lane & 15) * 128) + ((((lane >> 4) * 16) + 64) ^ ((lane & 7) << 4));
  const int bsub = wave & 3, npair = wave >> 2;

  f32x4 c0 = {0.f, 0.f, 0.f, 0.f}, c1 = {0.f, 0.f, 0.f, 0.f};
  #pragma unroll
  for (int kc = 0; kc < 8; ++kc) {
    const char* ab = At + kc * 8192 + bsub * 2048;
    bf16x8 aL = *(const bf16x8*)(ab + lo);
    bf16x8 aH = *(const bf16x8*)(ab + hi);
    const char* bb0 = Bt + kc * 8192 + (npair * 2) * 2048;
    const char* bb1 = bb0 + 2048;
    c0 = __builtin_amdgcn_mfma_f32_16x16x32_bf16(aL, *(const bf16x8*)(bb0 + lo), c0, 0, 0, 0);
    c0 = __builtin_amdgcn_mfma_f32_16x16x32_bf16(aH, *(const bf16x8*)(bb0 + hi), c0, 0, 0, 0);
    c1 = __builtin_amdgcn_mfma_f32_16x16x32_bf16(aL, *(const bf16x8*)(bb1 + lo), c1, 0, 0, 0);
    c1 = __builtin_amdgcn_mfma_f32_16x16x32_bf16(aH, *(const bf16x8*)(bb1 + hi), c1, 0, 0, 0);
  }
  unsigned short* U = (unsigned short*)ws_u;
  const int brow = b0 + bsub * 16 + (lane >> 4) * 4;
  const int nc0 = n0 + (npair * 2) * 16 + (lane & 15);
  #pragma unroll
  for (int r = 0; r < 4; ++r) {
    U[(size_t)(brow + r) * 4096 + nc0] = f2bf(c0[r]);
    U[(size_t)(brow + r) * 4096 + nc0 + 16] = f2bf(c1[r]);
  }
}

// ================= K2: batch-local spatial attention =================
__global__ __launch_bounds__(512)
void k2_attn(const float* __restrict__ x, const char* __restrict__ ws_u,
             char* __restrict__ ws_y) {
  __shared__ float ul[8 * 512];
  __shared__ float scoreL[8 * 64];
  __shared__ float pT[64 * 8];
  const int t = threadIdx.x;
  const int lane = t & 63;
  const int wave = t >> 6;
  const int b = blockIdx.x;
  const float* xb = x + (size_t)b * NP * DIM;

  {
    uint4 v = ((const uint4*)(ws_u + (size_t)b * 8192))[t];
    const unsigned short* pv = (const unsigned short*)&v;
    float* d = ul + t * 8;
    #pragma unroll
    for (int g = 0; g < 8; ++g) d[g] = bf2f(pv[g]);
  }
  __syncthreads();

  {
    float4 uf0[8], uf1[8];
    #pragma unroll
    for (int h = 0; h < 8; ++h) {
      uf0[h] = *(const float4*)(ul + h * 512 + 4 * lane);
      uf1[h] = *(const float4*)(ul + h * 512 + 256 + 4 * lane);
    }
    #pragma unroll 2
    for (int i = 0; i < 8; ++i) {
      const int m = wave * 8 + i;
      const float4* xr = (const float4*)(xb + (size_t)m * DIM);
      float4 xv0 = xr[lane];
      float4 xv1 = xr[64 + lane];
      #pragma unroll
      for (int h = 0; h < 8; ++h) {
        float p = xv0.x * uf0[h].x + xv0.y * uf0[h].y + xv0.z * uf0[h].z + xv0.w * uf0[h].w
                + xv1.x * uf1[h].x + xv1.y * uf1[h].y + xv1.z * uf1[h].z + xv1.w * uf1[h].w;
        p += __shfl_xor(p, 1);
        p += __shfl_xor(p, 2);
        p += __shfl_xor(p, 4);
        p += __shfl_xor(p, 8);
        p += __shfl_xor(p, 16);
        p += __shfl_xor(p, 32);
        if (lane == 0) scoreL[h * 64 + m] = p;
      }
    }
  }
  __syncthreads();

  {
    float sc = scoreL[wave * 64 + lane] * SCALE;
    float mx = sc;
    #pragma unroll
    for (int off = 32; off > 0; off >>= 1)
      mx = fmaxf(mx, __shfl_xor(mx, off));
    float ev = __expf(sc - mx);
    float sm = ev;
    #pragma unroll
    for (int off = 32; off > 0; off >>= 1)
      sm += __shfl_xor(sm, off);
    pT[lane * NH + wave] = ev / sm;
  }
  __syncthreads();

  {
    float acc[NH];
    #pragma unroll
    for (int h = 0; h < NH; ++h) acc[h] = 0.f;
    #pragma unroll 2
    for (int m = 0; m < NP; ++m) {
      float xv = xb[(size_t)m * DIM + t];
      const float4* pp = (const float4*)(pT + m * NH);
      float4 p0 = pp[0], p1 = pp[1];
      acc[0] = fmaf(p0.x, xv, acc[0]);
      acc[1] = fmaf(p0.y, xv, acc[1]);
      acc[2] = fmaf(p0.z, xv, acc[2]);
      acc[3] = fmaf(p0.w, xv, acc[3]);
      acc[4] = fmaf(p1.x, xv, acc[4]);
      acc[5] = fmaf(p1.y, xv, acc[5]);
      acc[6] = fmaf(p1.z, xv, acc[6]);
      acc[7] = fmaf(p1.w, xv, acc[7]);
    }
    unsigned short* Y = (unsigned short*)ws_y;
    #pragma unroll
    for (int h = 0; h < NH; ++h)
      Y[(size_t)b * 4096 + h * 512 + t] = f2bf(acc[h]);
  }
}

// ================= KS: S partials via K-split. grid 256 = bt(4) x et(8) x sl(8) =================
__global__ __launch_bounds__(512, 2)
void ks_s(const char* __restrict__ ws_y, const char* __restrict__ ws_pt,
          float* __restrict__ Spart) {
  extern __shared__ char sm[];
  char* At = sm;
  char* Bt = sm + 65536;
  const int t = threadIdx.x, lane = t & 63, wave = t >> 6;
  const int bt = blockIdx.x >> 6, et = (blockIdx.x >> 3) & 7, sl = blockIdx.x & 7;
  const int b0 = bt * 64, e0 = et * 64;
  const size_t kb2 = (size_t)sl * 1024;

  #pragma unroll
  for (int i = 0; i < 8; ++i) {
    const int r = wave * 8 + i;
    const int byt = (16 * (lane & 7)) ^ ((r & 7) << 4);
    uint4 va = ((const uint4*)(ws_y + (size_t)(b0 + r) * 8192 + kb2))[lane];
    *(uint4*)(At + (lane >> 3) * 8192 + r * 128 + byt) = va;
    uint4 vb = ((const uint4*)(ws_pt + (size_t)(e0 + r) * 8192 + kb2))[lane];
    *(uint4*)(Bt + (lane >> 3) * 8192 + r * 128 + byt) = vb;
  }
  __syncthreads();

  const int lo = ((lane & 15) * 128) + (((lane >> 4) * 16) ^ ((lane & 7) << 4));
  const int hi = ((lane & 15) * 128) + ((((lane >> 4) * 16) + 64) ^ ((lane & 7) << 4));
  const int bsub = wave & 3, epair = wave >> 2;

  f32x4 c0 = {0.f, 0.f, 0.f, 0.f}, c1 = {0.f, 0.f, 0.f, 0.f};
  #pragma unroll
  for (int kc = 0; kc < 8; ++kc) {
    const char* ab = At + kc * 8192 + bsub * 2048;
    bf16x8 aL = *(const bf16x8*)(ab + lo);
    bf16x8 aH = *(const bf16x8*)(ab + hi);
    const char* bb0 = Bt + kc * 8192 + (epair * 2) * 2048;
    const char* bb1 = bb0 + 2048;
    c0 = __builtin_amdgcn_mfma_f32_16x16x32_bf16(aL, *(const bf16x8*)(bb0 + lo), c0, 0, 0, 0);
    c0 = __builtin_amdgcn_mfma_f32_16x16x32_bf16(aH, *(const bf16x8*)(bb0 + hi), c0, 0, 0, 0);
    c1 = __builtin_amdgcn_mfma_f32_16x16x32_bf16(aL, *(const bf16x8*)(bb1 + lo), c1, 0, 0, 0);
    c1 = __builtin_amdgcn_mfma_f32_16x16x32_bf16(aH, *(const bf16x8*)(bb1 + hi), c1, 0, 0, 0);
  }
  const int brow = b0 + bsub * 16 + (lane >> 4) * 4;
  const int ec0 = e0 + (epair * 2) * 16 + (lane & 15);
  #pragma unroll
  for (int r = 0; r < 4; ++r) {
    Spart[((size_t)sl * 256 + brow + r) * 512 + ec0] = c0[r];
    Spart[((size_t)sl * 256 + brow + r) * 512 + ec0 + 16] = c1[r];
  }
}

// ================= K4: spectral phase — 1024 threads / 16 waves (grid=CU-count fix) =================
// region0 [0,65536): xT (stage+W2) -> w2T (phase C) -> wpart f32[16][512] (final reduce)
// Cc [65536,73728) ; s_l [73728,75776)
#define K4_LDS 75776
__global__ __launch_bounds__(1024)
void k4_spec(const float* __restrict__ x, const char* __restrict__ Cws,
             const float* __restrict__ Spart, const float* __restrict__ bout,
             float* __restrict__ out) {
  extern __shared__ char smem[];
  char* region0 = smem;
  char* Cc = smem + 65536;
  float* s_l = (float*)(smem + 73728);

  const int t = threadIdx.x;
  const int lane = t & 63;
  const int wave = t >> 6;  // 0..15
  const int b = blockIdx.x;
  const float* xb = x + (size_t)b * NP * DIM;

  const int lo_off = ((lane & 15) * 128) + ((((lane >> 4) * 16)) ^ ((lane & 7) << 4));
  const int hi_off = ((lane & 15) * 128) + ((((lane >> 4) * 16) + 64) ^ ((lane & 7) << 4));

  // ---- stage xT (bf16, swizzled): thread halves split the 8 m-column groups ----
  {
    const int d = t & 511;
    const int cbase = (t >> 9) * 4;  // 0 or 4
    #pragma unroll
    for (int ci = 0; ci < 4; ++ci) {
      const int c = cbase + ci;
      float v0 = xb[(c * 8 + 0) * DIM + d];
      float v1 = xb[(c * 8 + 1) * DIM + d];
      float v2 = xb[(c * 8 + 2) * DIM + d];
      float v3 = xb[(c * 8 + 3) * DIM + d];
      float v4 = xb[(c * 8 + 4) * DIM + d];
      float v5 = xb[(c * 8 + 5) * DIM + d];
      float v6 = xb[(c * 8 + 6) * DIM + d];
      float v7 = xb[(c * 8 + 7) * DIM + d];
      uint4 pk;
      pk.x = pk2(v0, v1);
      pk.y = pk2(v2, v3);
      pk.z = pk2(v4, v5);
      pk.w = pk2(v6, v7);
      *(uint4*)(region0 + d * 128 + ((c * 16) ^ ((d & 7) << 4))) = pk;
    }
    if (t < 512) {
      ((uint4*)Cc)[t] = ((const uint4*)Cws)[t];
      float sacc = bout[t];
      #pragma unroll
      for (int sl = 0; sl < 8; ++sl)
        sacc += Spart[((size_t)sl * 256 + b) * 512 + t];
      s_l[t] = sacc;
    }
  }
  __syncthreads();

  // ---- load phase-C A-fragments (2 passes x 16 waves) into registers ----
  bf16x8 pa0[2], pa1[2];
  #pragma unroll
  for (int pass = 0; pass < 2; ++pass) {
    const int d0 = pass * 256 + wave * 16;
    pa0[pass] = *(const bf16x8*)(region0 + d0 * 128 + lo_off);
    pa1[pass] = *(const bf16x8*)(region0 + d0 * 128 + hi_off);
  }

  // ---- W2-MFMA into packed registers (region0 still = xT); 2 e-tiles per wave ----
  uint2 pkW2[2][4];  // [etl][mt]
  {
    bf16x8 af0[4], af1[4];
    #pragma unroll
    for (int mt = 0; mt < 4; ++mt) {
      af0[mt] = *(const bf16x8*)(Cc + mt * 16 * 128 + lo_off);
      af1[mt] = *(const bf16x8*)(Cc + mt * 16 * 128 + hi_off);
    }
    #pragma unroll
    for (int etl = 0; etl < 2; ++etl) {
      const int e0 = (wave * 2 + etl) * 16;
      bf16x8 b0 = *(const bf16x8*)(region0 + e0 * 128 + lo_off);
      bf16x8 b1 = *(const bf16x8*)(region0 + e0 * 128 + hi_off);
      #pragma unroll
      for (int mt = 0; mt < 4; ++mt) {
        f32x4 c = {0.f, 0.f, 0.f, 0.f};
        c = __builtin_amdgcn_mfma_f32_16x16x32_bf16(af0[mt], b0, c, 0, 0, 0);
        c = __builtin_amdgcn_mfma_f32_16x16x32_bf16(af1[mt], b1, c, 0, 0, 0);
        pkW2[etl][mt].x = pk2(c[0], c[1]);
        pkW2[etl][mt].y = pk2(c[2], c[3]);
      }
    }
  }
  __syncthreads();  // all waves done reading xT

  // ---- write w2T (bf16, swizzled) into region0, overwriting xT ----
  {
    #pragma unroll
    for (int etl = 0; etl < 2; ++etl) {
      const int e = (wave * 2 + etl) * 16 + (lane & 15);
      #pragma unroll
      for (int mt = 0; mt < 4; ++mt) {
        const int mrow = mt * 16 + (lane >> 4) * 4;
        *(uint2*)(region0 + e * 128 + ((mrow * 2) ^ ((e & 7) << 4))) = pkW2[etl][mt];
      }
    }
  }
  __syncthreads();

  // ---- phase C: two-pass chunked softmax; A-frags from regs, w2T from region0 ----
  float treg[32];
  #pragma unroll
  for (int et = 0; et < 32; ++et) treg[et] = 0.f;

  #pragma unroll
  for (int pass = 0; pass < 2; ++pass) {
    const int d0 = pass * 256 + wave * 16;
    bf16x8 a0 = pa0[pass];
    bf16x8 a1 = pa1[pass];

    float rs[4] = {0.f, 0.f, 0.f, 0.f};
    #pragma unroll 4
    for (int et = 0; et < 32; ++et) {
      bf16x8 b0 = *(const bf16x8*)(region0 + et * 2048 + lo_off);
      bf16x8 b1 = *(const bf16x8*)(region0 + et * 2048 + hi_off);
      f32x4 c = {0.f, 0.f, 0.f, 0.f};
      c = __builtin_amdgcn_mfma_f32_16x16x32_bf16(a0, b0, c, 0, 0, 0);
      c = __builtin_amdgcn_mfma_f32_16x16x32_bf16(a1, b1, c, 0, 0, 0);
      rs[0] += __expf(c[0]);
      rs[1] += __expf(c[1]);
      rs[2] += __expf(c[2]);
      rs[3] += __expf(c[3]);
    }
    #pragma unroll
    for (int r = 0; r < 4; ++r) {
      rs[r] += __shfl_xor(rs[r], 1);
      rs[r] += __shfl_xor(rs[r], 2);
      rs[r] += __shfl_xor(rs[r], 4);
      rs[r] += __shfl_xor(rs[r], 8);
    }
    float coef[4];
    #pragma unroll
    for (int r = 0; r < 4; ++r)
      coef[r] = s_l[d0 + (lane >> 4) * 4 + r] / rs[r];

    #pragma unroll 4
    for (int et = 0; et < 32; ++et) {
      bf16x8 b0 = *(const bf16x8*)(region0 + et * 2048 + lo_off);
      bf16x8 b1 = *(const bf16x8*)(region0 + et * 2048 + hi_off);
      f32x4 c = {0.f, 0.f, 0.f, 0.f};
      c = __builtin_amdgcn_mfma_f32_16x16x32_bf16(a0, b0, c, 0, 0, 0);
      c = __builtin_amdgcn_mfma_f32_16x16x32_bf16(a1, b1, c, 0, 0, 0);
      float tp = treg[et];
      tp = fmaf(coef[0], __expf(c[0]), tp);
      tp = fmaf(coef[1], __expf(c[1]), tp);
      tp = fmaf(coef[2], __expf(c[2]), tp);
      tp = fmaf(coef[3], __expf(c[3]), tp);
      treg[et] = tp;
    }
  }
  __syncthreads();  // done reading w2T; region0 becomes partial buffer

  #pragma unroll
  for (int et = 0; et < 32; ++et) {
    treg[et] += __shfl_xor(treg[et], 16);
    treg[et] += __shfl_xor(treg[et], 32);
  }
  float* wpart = (float*)region0;  // [16][512]
  if (lane < 16) {
    #pragma unroll
    for (int et = 0; et < 32; ++et)
      wpart[wave * 512 + et * 16 + lane] = treg[et];
  }
  __syncthreads();

  const int e = t & 511;
  float tf = 0.f;
  #pragma unroll
  for (int w = 0; w < 16; ++w) tf += wpart[w * 512 + e];

  const int n0 = (t >> 9) * 32;
  float* ob = out + (size_t)b * NP * DIM + e;
  #pragma unroll 4
  for (int n = n0; n < n0 + 32; ++n) ob[n * DIM] = tf;
}

extern "C" void kernel_launch(void* const* d_in, const int* in_sizes, int n_in,
                              void* d_out, int out_size, void* d_ws, size_t ws_size,
                              hipStream_t stream) {
  (void)in_sizes; (void)n_in; (void)out_size; (void)ws_size;
  const float* x     = (const float*)d_in[0];
  const float* Wq    = (const float*)d_in[1];
  const float* Wkv   = (const float*)d_in[2];
  const float* Wout  = (const float*)d_in[3];
  const float* bout  = (const float*)d_in[4];
  const float* Wspec = (const float*)d_in[5];
  float* out = (float*)d_out;

  char* ws = (char*)d_ws;

  hipFuncSetAttribute(reinterpret_cast<const void*>(ku_u),
                      hipFuncAttributeMaxDynamicSharedMemorySize, GEMM_LDS);
  hipFuncSetAttribute(reinterpret_cast<const void*>(ks_s),
                      hipFuncAttributeMaxDynamicSharedMemorySize, GEMM_LDS);
  hipFuncSetAttribute(reinterpret_cast<const void*>(k4_spec),
                      hipFuncAttributeMaxDynamicSharedMemorySize, K4_LDS);

  kw_prep<<<dim3(1025), dim3(512), 0, stream>>>(Wq, Wkv, Wout, Wspec, ws);
  ku_u   <<<dim3(256),  dim3(512), GEMM_LDS, stream>>>(x, ws, ws + WS_U);
  k2_attn<<<dim3(256),  dim3(512), 0, stream>>>(x, ws + WS_U, ws + WS_Y);
  ks_s   <<<dim3(256),  dim3(512), GEMM_LDS, stream>>>(ws + WS_Y, ws + WS_PT,
                                                       (float*)(ws + WS_MT));
  k4_spec<<<dim3(256),  dim3(1024), K4_LDS, stream>>>(x, ws, (const float*)(ws + WS_MT),
                                                      bout, out);
}